// Round 8
// baseline (122.198 us; speedup 1.0000x reference)
//
#include <hip/hip_runtime.h>
#include <hip/hip_fp16.h>

#define T_IN 1024
#define D_DIM 512
#define T_OUT 1280
#define NPAIR 4096   // 8 * 512

// ---------------------------------------------------------------------------
// K1: transpose (b, t, d) -> (b, d, t), 64x64 LDS tiles.
// Also builds (in its first 4 (x,0,0) blocks):
//   tw[m]   fp64 (cos, -sin)(2 pi m/1024)  m=0..1023   (DFT twiddles)
//   rotf[m] fp32 (cos,  sin)(2 pi m/1024)  m=0..1023   (recon rotation table)
// ---------------------------------------------------------------------------
__global__ __launch_bounds__(256) void transpose_kernel(const float* __restrict__ x,
                                                        float* __restrict__ xt,
                                                        double2* __restrict__ tw,
                                                        float2* __restrict__ rotf) {
    __shared__ float tile[64][65];
    const int b  = blockIdx.z;
    const int t0 = blockIdx.y * 64;
    const int d0 = blockIdx.x * 64;
    const int dl = threadIdx.x & 63;
    const int r0 = threadIdx.x >> 6;   // 0..3

    if (blockIdx.x < 4 && blockIdx.y == 0 && blockIdx.z == 0) {
        int m = blockIdx.x * 256 + threadIdx.x;
        double th = (6.283185307179586476925286766559 / 1024.0) * (double)m;
        double c = cos(th), s = sin(th);
        tw[m]   = make_double2(c, -s);
        rotf[m] = make_float2((float)c, (float)s);
    }

#pragma unroll
    for (int i = 0; i < 16; ++i) {
        int tl = r0 * 16 + i;
        tile[tl][dl] = x[((size_t)b * T_IN + (t0 + tl)) * D_DIM + d0 + dl];
    }
    __syncthreads();
#pragma unroll
    for (int i = 0; i < 16; ++i) {
        int dl2 = r0 * 16 + i;
        xt[((size_t)b * D_DIM + (d0 + dl2)) * T_IN + t0 + dl] = tile[dl][dl2];
    }
}

// ---------------------------------------------------------------------------
// eighth-table twiddle lookup: e^{-2 pi i m/1024}, m in [0, 1024)
// ---------------------------------------------------------------------------
__device__ __forceinline__ double2 TW8(const double2* __restrict__ E, int m) {
    int r = m & 255;
    int q = (m >> 8) & 3;
    double c, s;
    if (r <= 128) { double2 t = E[r];       c = t.x; s = t.y; }
    else          { double2 t = E[256 - r]; c = t.y; s = t.x; }
    double C, S;
    switch (q) {
        case 0:  C = c;  S = s;  break;
        case 1:  C = -s; S = c;  break;
        case 2:  C = -c; S = -s; break;
        default: C = s;  S = -c; break;
    }
    return make_double2(C, -S);
}

// ---------------------------------------------------------------------------
// K2: per (b,d): stats -> standardize/clip -> even/odd butterfly -> 1024-pt
// real DFT (32x32 Cooley-Tukey, fp64) -> fp64 amp^2 sort-keys + half phase.
// ---------------------------------------------------------------------------
__global__ __launch_bounds__(256) void dft_kernel(const float* __restrict__ xt,
                                                  const double2* __restrict__ twg,
                                                  float2* __restrict__ stats,
                                                  double* __restrict__ keys,
                                                  __half* __restrict__ phase) {
    __shared__ double2 uni[1024];       // phase A: xs (1024 dbl); phase B: S[32][32]
    __shared__ double2 tw_s[130];       // eighth table E[0..128]
    __shared__ double  red_s[16];
    double* xs_s = (double*)uni;

    const int tid  = threadIdx.x;
    const int pair = blockIdx.x;

    const float4 v = reinterpret_cast<const float4*>(xt + (size_t)pair * T_IN)[tid];

    if (tid < 130) {
        double2 t = twg[tid];                 // (cos, -sin)
        tw_s[tid] = make_double2(t.x, -t.y);  // store (cos, +sin)
    }

    // --- stats (fp64, deterministic tree reduce; final sum redundant per-thread) ---
    double sum = (double)v.x + (double)v.y + (double)v.z + (double)v.w;
    double sq  = (double)v.x * v.x + (double)v.y * v.y +
                 (double)v.z * v.z + (double)v.w * v.w;
#pragma unroll
    for (int off = 32; off; off >>= 1) {
        sum += __shfl_down(sum, off);
        sq  += __shfl_down(sq, off);
    }
    const int wv = tid >> 6;
    if ((tid & 63) == 0) { red_s[wv] = sum; red_s[8 + wv] = sq; }
    __syncthreads();
    double mean, stdp;
    {
        double s = red_s[0] + red_s[1] + red_s[2] + red_s[3];
        double q = red_s[8] + red_s[9] + red_s[10] + red_s[11];
        mean = s * (1.0 / 1024.0);
        double var = (q - 1024.0 * mean * mean) * (1.0 / 1023.0);
        var = var > 0.0 ? var : 0.0;
        stdp = sqrt(var) + 1e-8;   // reference: std + 1e-8
        if (tid == 0) stats[pair] = make_float2((float)mean, (float)stdp);
    }
    const double inv = 1.0 / stdp;
    {
        double z0 = ((double)v.x - mean) * inv;
        double z1 = ((double)v.y - mean) * inv;
        double z2 = ((double)v.z - mean) * inv;
        double z3 = ((double)v.w - mean) * inv;
        z0 = fmin(2.0, fmax(-2.0, z0)) + 1e-9;
        z1 = fmin(2.0, fmax(-2.0, z1)) + 1e-9;
        z2 = fmin(2.0, fmax(-2.0, z2)) + 1e-9;
        z3 = fmin(2.0, fmax(-2.0, z3)) + 1e-9;
        xs_s[tid * 4 + 0] = z0;
        xs_s[tid * 4 + 1] = z1;
        xs_s[tid * 4 + 2] = z2;
        xs_s[tid * 4 + 3] = z3;
    }
    __syncthreads();

    // --- in-place even/odd butterfly over t1 (pairs t1 <-> 32-t1, t1=1..15) ---
    {
        int idx = tid;
#pragma unroll
        for (int rr = 0; rr < 2; ++rr) {
            if (idx < 480) {
                int t1p = 1 + (idx >> 5);
                int t2c = idx & 31;
                int ia = t1p * 32 + t2c;
                int ib = (32 - t1p) * 32 + t2c;
                double a = xs_s[ia], b = xs_s[ib];
                xs_s[ia] = a + b;
                xs_s[ib] = a - b;
            }
            idx += 256;
        }
    }
    __syncthreads();

    const int k1 = tid & 31;
    const int g  = tid >> 5;   // 0..7

    // --- stage 1 (into registers) ---
    double2 R0, R1, R2, R3;
    {
        const double2 w = TW8(tw_s, k1 * 32);   // e^{-2 pi i k1/32}
        const double sgn16 = (k1 & 1) ? -1.0 : 1.0;

        double ar0 = xs_s[g]      + sgn16 * xs_s[512 + g];
        double ar1 = xs_s[g + 8]  + sgn16 * xs_s[512 + g + 8];
        double ar2 = xs_s[g + 16] + sgn16 * xs_s[512 + g + 16];
        double ar3 = xs_s[g + 24] + sgn16 * xs_s[512 + g + 24];
        double ai0 = 0, ai1 = 0, ai2 = 0, ai3 = 0;

        double c = w.x, s = w.y;   // t1 = 1
#pragma unroll 5
        for (int t1 = 1; t1 <= 15; ++t1) {
            const double* eb = &xs_s[t1 * 32];
            const double* ob = &xs_s[(32 - t1) * 32];
            ar0 = fma(eb[g], c, ar0);      ai0 = fma(ob[g], s, ai0);
            ar1 = fma(eb[g + 8], c, ar1);  ai1 = fma(ob[g + 8], s, ai1);
            ar2 = fma(eb[g + 16], c, ar2); ai2 = fma(ob[g + 16], s, ai2);
            ar3 = fma(eb[g + 24], c, ar3); ai3 = fma(ob[g + 24], s, ai3);
            double cn = c * w.x - s * w.y;
            double sn = s * w.x + c * w.y;
            c = cn; s = sn;
        }
        {
            double2 tm = TW8(tw_s, g * k1);
            R0 = make_double2(ar0 * tm.x - ai0 * tm.y, ar0 * tm.y + ai0 * tm.x);
        }
        {
            double2 tm = TW8(tw_s, (g + 8) * k1);
            R1 = make_double2(ar1 * tm.x - ai1 * tm.y, ar1 * tm.y + ai1 * tm.x);
        }
        {
            double2 tm = TW8(tw_s, (g + 16) * k1);
            R2 = make_double2(ar2 * tm.x - ai2 * tm.y, ar2 * tm.y + ai2 * tm.x);
        }
        {
            double2 tm = TW8(tw_s, (g + 24) * k1);
            R3 = make_double2(ar3 * tm.x - ai3 * tm.y, ar3 * tm.y + ai3 * tm.x);
        }
    }
    __syncthreads();   // xs reads done -> overwrite union with S

    uni[g * 32 + k1]        = R0;
    uni[(g + 8) * 32 + k1]  = R1;
    uni[(g + 16) * 32 + k1] = R2;
    uni[(g + 24) * 32 + k1] = R3;
    __syncthreads();

    // --- stage 2: bins k2 = g and g+8 via (-i)^t2 trick, one recurrence ---
    {
        const double2 wa = TW8(tw_s, 32 * g);   // e^{-2 pi i g/32}
        double ca = 1.0, sa = 0.0;
        double Ar = 0, Ai = 0, Br = 0, Bi = 0;
#pragma unroll
        for (int u = 0; u < 8; ++u) {
            {
                double2 S = uni[(4 * u + 0) * 32 + k1];
                double P = fma(S.x, ca, -(S.y * sa));
                double Q = fma(S.x, sa,  (S.y * ca));
                Ar += P; Ai += Q; Br += P; Bi += Q;
                double cn = fma(ca, wa.x, -(sa * wa.y));
                double sn = fma(sa, wa.x,  (ca * wa.y));
                ca = cn; sa = sn;
            }
            {
                double2 S = uni[(4 * u + 1) * 32 + k1];
                double P = fma(S.x, ca, -(S.y * sa));
                double Q = fma(S.x, sa,  (S.y * ca));
                Ar += P; Ai += Q; Br += Q; Bi -= P;
                double cn = fma(ca, wa.x, -(sa * wa.y));
                double sn = fma(sa, wa.x,  (ca * wa.y));
                ca = cn; sa = sn;
            }
            {
                double2 S = uni[(4 * u + 2) * 32 + k1];
                double P = fma(S.x, ca, -(S.y * sa));
                double Q = fma(S.x, sa,  (S.y * ca));
                Ar += P; Ai += Q; Br -= P; Bi -= Q;
                double cn = fma(ca, wa.x, -(sa * wa.y));
                double sn = fma(sa, wa.x,  (ca * wa.y));
                ca = cn; sa = sn;
            }
            {
                double2 S = uni[(4 * u + 3) * 32 + k1];
                double P = fma(S.x, ca, -(S.y * sa));
                double Q = fma(S.x, sa,  (S.y * ca));
                Ar += P; Ai += Q; Br -= Q; Bi += P;
                double cn = fma(ca, wa.x, -(sa * wa.y));
                double sn = fma(sa, wa.x,  (ca * wa.y));
                ca = cn; sa = sn;
            }
        }
        const int ka = k1 + 32 * g;          // == tid
        const int kb = k1 + 32 * (g + 8);    // == tid + 256
        const size_t base = (size_t)pair * 512;

        // amp^2 keys (ordering identical to amp; sqrt deferred to winners)
        double a2a = Ar * Ar + Ai * Ai;
        double a2b = Br * Br + Bi * Bi;
        unsigned long long bba = __double_as_longlong(a2a);
        unsigned long long bbb = __double_as_longlong(a2b);
        double keya = __longlong_as_double((bba & ~1023ULL) |
                                           (unsigned long long)(1023 - ka));
        double keyb = __longlong_as_double((bbb & ~1023ULL) |
                                           (unsigned long long)(1023 - kb));
        if (ka == 0) keya = -1.0;   // DC excluded
        keys[base + ka] = keya;
        keys[base + kb] = keyb;
        phase[base + ka] = __float2half(atan2f((float)Ai, (float)Ar));
        phase[base + kb] = __float2half(atan2f((float)Bi, (float)Br));
    }
}

// ---------------------------------------------------------------------------
// K2b: top-32 per pair, one WAVE per pair.  sel = (amp, cos(ph), sin(ph), k)
// ---------------------------------------------------------------------------
__global__ __launch_bounds__(256) void topk_kernel(const double* __restrict__ keys,
                                                   const __half* __restrict__ phase,
                                                   float4* __restrict__ sel) {
    const int tid  = threadIdx.x;
    const int lane = tid & 63;
    const int pair = blockIdx.x * 4 + (tid >> 6);
    const size_t base = (size_t)pair * 512;

    double kreg[8];
#pragma unroll
    for (int j = 0; j < 8; ++j) kreg[j] = keys[base + j * 64 + lane];

    double win = -2.0;
    for (int r = 0; r < 32; ++r) {
        double m01 = fmax(kreg[0], kreg[1]);
        double m23 = fmax(kreg[2], kreg[3]);
        double m45 = fmax(kreg[4], kreg[5]);
        double m67 = fmax(kreg[6], kreg[7]);
        double m = fmax(fmax(m01, m23), fmax(m45, m67));
#pragma unroll
        for (int off = 1; off < 64; off <<= 1)
            m = fmax(m, __shfl_xor(m, off));
#pragma unroll
        for (int j = 0; j < 8; ++j)
            if (kreg[j] == m) kreg[j] = -2.0;   // exact bit match (keys unique)
        if (lane == r) win = m;
    }

    if (lane < 32) {
        unsigned long long b = __double_as_longlong(win);
        int k = 1023 - (int)(b & 1023ULL);
        float ph = __half2float(phase[base + k]);
        float sp, cp;
        __sincosf(ph, &sp, &cp);
        double amp = sqrt(win);   // win = amp^2 (packed bits, rel err 2^-43)
        float aout = (float)(2.0 * amp / (1024.0 + 1e-8));
        sel[(size_t)pair * 32 + lane] = make_float4(aout, cp, sp, (float)k);
    }
}

// ---------------------------------------------------------------------------
// K2-fallback (monolithic dft+topk), used if ws too small
// ---------------------------------------------------------------------------
__global__ __launch_bounds__(256) void dft_topk_kernel(const float* __restrict__ xt,
                                                       const double2* __restrict__ twg,
                                                       float2* __restrict__ stats,
                                                       float4* __restrict__ sel) {
    __shared__ double  xs_s[1024];
    __shared__ double2 tw_s[1024];
    __shared__ double2 S_s[32][32];
    __shared__ double2 spec_s[512];
    __shared__ double  amp_s[512];
    __shared__ double  red_s[16];
    __shared__ double  bc_s[2];

    const int tid  = threadIdx.x;
    const int pair = blockIdx.x;
    const float4 v = reinterpret_cast<const float4*>(xt + (size_t)pair * T_IN)[tid];
#pragma unroll
    for (int i = 0; i < 4; ++i) tw_s[tid + 256 * i] = twg[tid + 256 * i];

    double sum = (double)v.x + (double)v.y + (double)v.z + (double)v.w;
    double sq  = (double)v.x * v.x + (double)v.y * v.y +
                 (double)v.z * v.z + (double)v.w * v.w;
#pragma unroll
    for (int off = 32; off; off >>= 1) {
        sum += __shfl_down(sum, off);
        sq  += __shfl_down(sq, off);
    }
    const int wv = tid >> 6;
    if ((tid & 63) == 0) { red_s[wv] = sum; red_s[8 + wv] = sq; }
    __syncthreads();
    if (tid == 0) {
        double s = red_s[0] + red_s[1] + red_s[2] + red_s[3];
        double q = red_s[8] + red_s[9] + red_s[10] + red_s[11];
        double mean = s * (1.0 / 1024.0);
        double var  = (q - 1024.0 * mean * mean) * (1.0 / 1023.0);
        var = var > 0.0 ? var : 0.0;
        double stdp = sqrt(var) + 1e-8;
        bc_s[0] = mean; bc_s[1] = stdp;
        stats[pair] = make_float2((float)mean, (float)stdp);
    }
    __syncthreads();
    const double mean = bc_s[0];
    const double inv  = 1.0 / bc_s[1];
    {
        double z0 = ((double)v.x - mean) * inv;
        double z1 = ((double)v.y - mean) * inv;
        double z2 = ((double)v.z - mean) * inv;
        double z3 = ((double)v.w - mean) * inv;
        z0 = fmin(2.0, fmax(-2.0, z0)) + 1e-9;
        z1 = fmin(2.0, fmax(-2.0, z1)) + 1e-9;
        z2 = fmin(2.0, fmax(-2.0, z2)) + 1e-9;
        z3 = fmin(2.0, fmax(-2.0, z3)) + 1e-9;
        xs_s[tid * 4 + 0] = z0; xs_s[tid * 4 + 1] = z1;
        xs_s[tid * 4 + 2] = z2; xs_s[tid * 4 + 3] = z3;
    }
    __syncthreads();
    const int k1 = tid & 31;
    const int g  = tid >> 5;
    {
        const double2 w = tw_s[k1 * 32];
        double c = 1.0, s = 0.0;
        double ar0 = 0, ai0 = 0, ar1 = 0, ai1 = 0;
        double ar2 = 0, ai2 = 0, ar3 = 0, ai3 = 0;
#pragma unroll 4
        for (int t1 = 0; t1 < 32; ++t1) {
            const double* xb = &xs_s[t1 * 32];
            double x0 = xb[g], x1 = xb[g + 8], x2 = xb[g + 16], x3 = xb[g + 24];
            ar0 = fma(x0, c, ar0); ai0 = fma(x0, s, ai0);
            ar1 = fma(x1, c, ar1); ai1 = fma(x1, s, ai1);
            ar2 = fma(x2, c, ar2); ai2 = fma(x2, s, ai2);
            ar3 = fma(x3, c, ar3); ai3 = fma(x3, s, ai3);
            double cn = c * w.x - s * w.y;
            double sn = s * w.x + c * w.y;
            c = cn; s = sn;
        }
        { double2 tm = tw_s[g * k1];
          S_s[g][k1] = make_double2(ar0 * tm.x - ai0 * tm.y, ar0 * tm.y + ai0 * tm.x); }
        { double2 tm = tw_s[(g + 8) * k1];
          S_s[g + 8][k1] = make_double2(ar1 * tm.x - ai1 * tm.y, ar1 * tm.y + ai1 * tm.x); }
        { double2 tm = tw_s[(g + 16) * k1];
          S_s[g + 16][k1] = make_double2(ar2 * tm.x - ai2 * tm.y, ar2 * tm.y + ai2 * tm.x); }
        { double2 tm = tw_s[(g + 24) * k1];
          S_s[g + 24][k1] = make_double2(ar3 * tm.x - ai3 * tm.y, ar3 * tm.y + ai3 * tm.x); }
    }
    __syncthreads();
    {
        const double2 wa = tw_s[32 * g];
        const double2 wb = tw_s[32 * (g + 8)];
        double ca = 1.0, sa = 0.0, cb = 1.0, sb = 0.0;
        double Ar = 0, Ai = 0, Br = 0, Bi = 0;
#pragma unroll 4
        for (int t2 = 0; t2 < 32; ++t2) {
            double2 S = S_s[t2][k1];
            Ar += S.x * ca - S.y * sa; Ai += S.x * sa + S.y * ca;
            Br += S.x * cb - S.y * sb; Bi += S.x * sb + S.y * cb;
            double cn = ca * wa.x - sa * wa.y;
            double sn = sa * wa.x + ca * wa.y;
            ca = cn; sa = sn;
            cn = cb * wb.x - sb * wb.y;
            sn = sb * wb.x + cb * wb.y;
            cb = cn; sb = sn;
        }
        const int ka = k1 + 32 * g;
        const int kb = k1 + 32 * (g + 8);
        spec_s[ka] = make_double2(Ar, Ai);
        amp_s[ka]  = (ka == 0) ? -1.0 : sqrt(Ar * Ar + Ai * Ai);
        spec_s[kb] = make_double2(Br, Bi);
        amp_s[kb]  = sqrt(Br * Br + Bi * Bi);
    }
    __syncthreads();
    if (tid < 64) {
        const int lane = tid;
        double a0 = amp_s[lane * 8 + 0], a1 = amp_s[lane * 8 + 1];
        double a2 = amp_s[lane * 8 + 2], a3 = amp_s[lane * 8 + 3];
        double a4 = amp_s[lane * 8 + 4], a5 = amp_s[lane * 8 + 5];
        double a6 = amp_s[lane * 8 + 6], a7 = amp_s[lane * 8 + 7];
        int my_sel = 0;
        for (int r = 0; r < 32; ++r) {
            double vmax = a0; int li = 0;
            if (a1 > vmax) { vmax = a1; li = 1; }
            if (a2 > vmax) { vmax = a2; li = 2; }
            if (a3 > vmax) { vmax = a3; li = 3; }
            if (a4 > vmax) { vmax = a4; li = 4; }
            if (a5 > vmax) { vmax = a5; li = 5; }
            if (a6 > vmax) { vmax = a6; li = 6; }
            if (a7 > vmax) { vmax = a7; li = 7; }
            int gi = lane * 8 + li;
#pragma unroll
            for (int off = 1; off < 64; off <<= 1) {
                double ov = __shfl_xor(vmax, off);
                int    og = __shfl_xor(gi, off);
                if (ov > vmax || (ov == vmax && og < gi)) { vmax = ov; gi = og; }
            }
            if ((gi >> 3) == lane) {
                switch (gi & 7) {
                    case 0: a0 = -2.0; break; case 1: a1 = -2.0; break;
                    case 2: a2 = -2.0; break; case 3: a3 = -2.0; break;
                    case 4: a4 = -2.0; break; case 5: a5 = -2.0; break;
                    case 6: a6 = -2.0; break; case 7: a7 = -2.0; break;
                }
            }
            if (lane == r) my_sel = gi;
        }
        if (lane < 32) {
            const int k = my_sel;
            double2 sp  = spec_s[k];
            double ampv = fmax(amp_s[k], 1e-30);
            double aout = 2.0 * amp_s[k] / (1024.0 + 1e-8);
            double ia   = 1.0 / ampv;
            sel[(size_t)pair * 32 + lane] =
                make_float4((float)aout, (float)(sp.x * ia), (float)(sp.y * ia),
                            (float)k);
        }
    }
}

// ---------------------------------------------------------------------------
// K3: rotation-based reconstruction. v4: chunked sel staging (8 js at a time,
// LDS 41.5K -> ~17.5K for occupancy) + split cos/sin tables (bank spread).
// ---------------------------------------------------------------------------
__global__ __launch_bounds__(256) void recon_kernel(const float4* __restrict__ sel,
                                                    const float2* __restrict__ stats,
                                                    const float2* __restrict__ rotf,
                                                    float* __restrict__ out) {
    __shared__ float4 sel_s[8][64];      // one 8-js chunk
    __shared__ float  rotc_s[1024];
    __shared__ float  rots_s[1024];
    __shared__ float2 st_s[64];
    const int bid   = blockIdx.x;
    const int chunk = bid & 31;
    const int dt    = (bid >> 5) & 7;
    const int b     = bid >> 8;
    const int d0    = dt * 64;
    const int tid   = threadIdx.x;

#pragma unroll
    for (int i = 0; i < 4; ++i) {
        float2 t = rotf[tid + 256 * i];
        rotc_s[tid + 256 * i] = t.x;
        rots_s[tid + 256 * i] = t.y;
    }
    if (tid < 64) st_s[tid] = stats[b * D_DIM + d0 + tid];

    const int dl    = tid & 63;
    const int wvv   = tid >> 6;
    const int tbase = chunk * 40 + wvv * 10;

    // staging index: j = tid&7 (consecutive lanes -> consecutive js -> 128B
    // contiguous global reads per d-channel), dls = tid>>3
    const int sj  = tid & 7;
    const int sdl = tid >> 3;   // 0..31; +32 on second iteration

    float acc[10];
#pragma unroll
    for (int j = 0; j < 10; ++j) acc[j] = 0.0f;

    for (int cs = 0; cs < 4; ++cs) {
        __syncthreads();   // prev chunk consumed (also covers rot/st on cs=0)
        sel_s[sj][sdl] =
            sel[((size_t)(b * D_DIM + d0 + sdl)) * 32 + cs * 8 + sj];
        sel_s[sj][sdl + 32] =
            sel[((size_t)(b * D_DIM + d0 + sdl + 32)) * 32 + cs * 8 + sj];
        __syncthreads();

#pragma unroll
        for (int js = 0; js < 8; ++js) {
            float4 tr = sel_s[js][dl];       // (a, cos ph, sin ph, k)
            const float a = tr.x;
            int k   = (int)tr.w;
            int mm0 = (k * tbase) & 1023;
            int m5  = (5 * k) & 1023;
            float t0c = rotc_s[mm0], t0s = rots_s[mm0];
            float tkc = rotc_s[k],   tks = rots_s[k];
            float t5c = rotc_s[m5],  t5s = rots_s[m5];

            float ca = t0c * tr.y - t0s * tr.z;
            float sa = t0s * tr.y + t0c * tr.z;
            float cb = ca * t5c - sa * t5s;
            float sb = sa * t5c + ca * t5s;
#pragma unroll
            for (int j = 0; j < 5; ++j) {
                acc[j]     = fmaf(a, ca, acc[j]);
                acc[j + 5] = fmaf(a, cb, acc[j + 5]);
                float can = ca * tkc - sa * tks;
                float san = sa * tkc + ca * tks;
                ca = can; sa = san;
                float cbn = cb * tkc - sb * tks;
                float sbn = sb * tkc + cb * tks;
                cb = cbn; sb = sbn;
            }
        }
    }
    const float2 st = st_s[dl];
#pragma unroll
    for (int j = 0; j < 10; ++j) {
        out[((size_t)b * T_OUT + (tbase + j)) * D_DIM + d0 + dl] =
            fmaf(acc[j], st.y, st.x);
    }
}

// ---------------------------------------------------------------------------
extern "C" void kernel_launch(void* const* d_in, const int* in_sizes, int n_in,
                              void* d_out, int out_size, void* d_ws, size_t ws_size,
                              hipStream_t stream) {
    const float* x = (const float*)d_in[0];
    float* out = (float*)d_out;
    char* ws = (char*)d_ws;
    const size_t MB = 1024 * 1024;

    if (ws_size >= 39 * MB) {
        // split-path layout (total ~38.2 MB, no overlaps):
        float*   xt    = (float*)ws;                          // 16 MB  [0,16)
        double*  keys  = (double*)(ws + 16 * MB);             // 16 MB  [16,32)
        __half*  phase = (__half*)(ws + 32 * MB);             //  4 MB  [32,36)
        double2* tw    = (double2*)(ws + 36 * MB);            // 16 KB
        float2*  stats = (float2*)(ws + 36 * MB + 65536);     // 32 KB
        float4*  sel   = (float4*)(ws + 36 * MB + 131072);    //  2 MB
        float2*  rotf  = (float2*)(ws + 38 * MB + 131072);    //  8 KB

        transpose_kernel<<<dim3(8, 16, 8), 256, 0, stream>>>(x, xt, tw, rotf);
        dft_kernel<<<NPAIR, 256, 0, stream>>>(xt, tw, stats, keys, phase);
        topk_kernel<<<NPAIR / 4, 256, 0, stream>>>(keys, phase, sel);
        recon_kernel<<<2048, 256, 0, stream>>>(sel, stats, rotf, out);
    } else {
        // fallback
        float*   xt    = (float*)ws;                                    // 16 MB
        double2* tw    = (double2*)(ws + 16 * MB);                      // 16 KB
        float2*  stats = (float2*)(ws + 16 * MB + 16384);               // 32 KB
        float4*  sel   = (float4*)(ws + 16 * MB + 16384 + 32768);       //  2 MB
        float2*  rotf  = (float2*)(ws + 16 * MB + 16384 + 32768 + 2 * MB); // 8 KB

        transpose_kernel<<<dim3(8, 16, 8), 256, 0, stream>>>(x, xt, tw, rotf);
        dft_topk_kernel<<<NPAIR, 256, 0, stream>>>(xt, tw, stats, sel);
        recon_kernel<<<2048, 256, 0, stream>>>(sel, stats, rotf, out);
    }
}

// Round 9
// 119.498 us; speedup vs baseline: 1.0226x; 1.0226x over previous
//
#include <hip/hip_runtime.h>
#include <hip/hip_fp16.h>

#define T_IN 1024
#define D_DIM 512
#define T_OUT 1280
#define NPAIR 4096   // 8 * 512

// ---------------------------------------------------------------------------
// K1: transpose (b, t, d) -> (b, d, t), 64x64 LDS tiles.
// Also builds fp64 twiddles tw[m] = (cos, -sin)(2 pi m/1024), m=0..1023,
// in its first 4 (x,0,0) blocks.
// ---------------------------------------------------------------------------
__global__ __launch_bounds__(256) void transpose_kernel(const float* __restrict__ x,
                                                        float* __restrict__ xt,
                                                        double2* __restrict__ tw) {
    __shared__ float tile[64][65];
    const int b  = blockIdx.z;
    const int t0 = blockIdx.y * 64;
    const int d0 = blockIdx.x * 64;
    const int dl = threadIdx.x & 63;
    const int r0 = threadIdx.x >> 6;   // 0..3

    if (blockIdx.x < 4 && blockIdx.y == 0 && blockIdx.z == 0) {
        int m = blockIdx.x * 256 + threadIdx.x;
        double th = (6.283185307179586476925286766559 / 1024.0) * (double)m;
        tw[m] = make_double2(cos(th), -sin(th));
    }

#pragma unroll
    for (int i = 0; i < 16; ++i) {
        int tl = r0 * 16 + i;
        tile[tl][dl] = x[((size_t)b * T_IN + (t0 + tl)) * D_DIM + d0 + dl];
    }
    __syncthreads();
#pragma unroll
    for (int i = 0; i < 16; ++i) {
        int dl2 = r0 * 16 + i;
        xt[((size_t)b * D_DIM + (d0 + dl2)) * T_IN + t0 + dl] = tile[dl][dl2];
    }
}

// ---------------------------------------------------------------------------
// eighth-table twiddle lookup: e^{-2 pi i m/1024}, m in [0, 1024)
// ---------------------------------------------------------------------------
__device__ __forceinline__ double2 TW8(const double2* __restrict__ E, int m) {
    int r = m & 255;
    int q = (m >> 8) & 3;
    double c, s;
    if (r <= 128) { double2 t = E[r];       c = t.x; s = t.y; }
    else          { double2 t = E[256 - r]; c = t.y; s = t.x; }
    double C, S;
    switch (q) {
        case 0:  C = c;  S = s;  break;
        case 1:  C = -s; S = c;  break;
        case 2:  C = -c; S = -s; break;
        default: C = s;  S = -c; break;
    }
    return make_double2(C, -S);
}

// ---------------------------------------------------------------------------
// K2: per (b,d): stats -> standardize/clip -> even/odd butterfly -> 1024-pt
// real DFT (32x32 Cooley-Tukey, fp64) -> fp64 amp^2 sort-keys + half phase.
// ---------------------------------------------------------------------------
__global__ __launch_bounds__(256) void dft_kernel(const float* __restrict__ xt,
                                                  const double2* __restrict__ twg,
                                                  float2* __restrict__ stats,
                                                  double* __restrict__ keys,
                                                  __half* __restrict__ phase) {
    __shared__ double2 uni[1024];       // phase A: xs (1024 dbl); phase B: S[32][32]
    __shared__ double2 tw_s[130];       // eighth table E[0..128]
    __shared__ double  red_s[16];
    double* xs_s = (double*)uni;

    const int tid  = threadIdx.x;
    const int pair = blockIdx.x;

    const float4 v = reinterpret_cast<const float4*>(xt + (size_t)pair * T_IN)[tid];

    if (tid < 130) {
        double2 t = twg[tid];                 // (cos, -sin)
        tw_s[tid] = make_double2(t.x, -t.y);  // store (cos, +sin)
    }

    // --- stats (fp64, deterministic tree reduce; final sum redundant per-thread) ---
    double sum = (double)v.x + (double)v.y + (double)v.z + (double)v.w;
    double sq  = (double)v.x * v.x + (double)v.y * v.y +
                 (double)v.z * v.z + (double)v.w * v.w;
#pragma unroll
    for (int off = 32; off; off >>= 1) {
        sum += __shfl_down(sum, off);
        sq  += __shfl_down(sq, off);
    }
    const int wv = tid >> 6;
    if ((tid & 63) == 0) { red_s[wv] = sum; red_s[8 + wv] = sq; }
    __syncthreads();
    double mean, stdp;
    {
        double s = red_s[0] + red_s[1] + red_s[2] + red_s[3];
        double q = red_s[8] + red_s[9] + red_s[10] + red_s[11];
        mean = s * (1.0 / 1024.0);
        double var = (q - 1024.0 * mean * mean) * (1.0 / 1023.0);
        var = var > 0.0 ? var : 0.0;
        stdp = sqrt(var) + 1e-8;   // reference: std + 1e-8
        if (tid == 0) stats[pair] = make_float2((float)mean, (float)stdp);
    }
    const double inv = 1.0 / stdp;
    {
        double z0 = ((double)v.x - mean) * inv;
        double z1 = ((double)v.y - mean) * inv;
        double z2 = ((double)v.z - mean) * inv;
        double z3 = ((double)v.w - mean) * inv;
        z0 = fmin(2.0, fmax(-2.0, z0)) + 1e-9;
        z1 = fmin(2.0, fmax(-2.0, z1)) + 1e-9;
        z2 = fmin(2.0, fmax(-2.0, z2)) + 1e-9;
        z3 = fmin(2.0, fmax(-2.0, z3)) + 1e-9;
        xs_s[tid * 4 + 0] = z0;
        xs_s[tid * 4 + 1] = z1;
        xs_s[tid * 4 + 2] = z2;
        xs_s[tid * 4 + 3] = z3;
    }
    __syncthreads();

    // --- in-place even/odd butterfly over t1 (pairs t1 <-> 32-t1, t1=1..15) ---
    {
        int idx = tid;
#pragma unroll
        for (int rr = 0; rr < 2; ++rr) {
            if (idx < 480) {
                int t1p = 1 + (idx >> 5);
                int t2c = idx & 31;
                int ia = t1p * 32 + t2c;
                int ib = (32 - t1p) * 32 + t2c;
                double a = xs_s[ia], b = xs_s[ib];
                xs_s[ia] = a + b;
                xs_s[ib] = a - b;
            }
            idx += 256;
        }
    }
    __syncthreads();

    const int k1 = tid & 31;
    const int g  = tid >> 5;   // 0..7

    // --- stage 1 (into registers) ---
    double2 R0, R1, R2, R3;
    {
        const double2 w = TW8(tw_s, k1 * 32);   // e^{-2 pi i k1/32}
        const double sgn16 = (k1 & 1) ? -1.0 : 1.0;

        double ar0 = xs_s[g]      + sgn16 * xs_s[512 + g];
        double ar1 = xs_s[g + 8]  + sgn16 * xs_s[512 + g + 8];
        double ar2 = xs_s[g + 16] + sgn16 * xs_s[512 + g + 16];
        double ar3 = xs_s[g + 24] + sgn16 * xs_s[512 + g + 24];
        double ai0 = 0, ai1 = 0, ai2 = 0, ai3 = 0;

        double c = w.x, s = w.y;   // t1 = 1
#pragma unroll 5
        for (int t1 = 1; t1 <= 15; ++t1) {
            const double* eb = &xs_s[t1 * 32];
            const double* ob = &xs_s[(32 - t1) * 32];
            ar0 = fma(eb[g], c, ar0);      ai0 = fma(ob[g], s, ai0);
            ar1 = fma(eb[g + 8], c, ar1);  ai1 = fma(ob[g + 8], s, ai1);
            ar2 = fma(eb[g + 16], c, ar2); ai2 = fma(ob[g + 16], s, ai2);
            ar3 = fma(eb[g + 24], c, ar3); ai3 = fma(ob[g + 24], s, ai3);
            double cn = c * w.x - s * w.y;
            double sn = s * w.x + c * w.y;
            c = cn; s = sn;
        }
        {
            double2 tm = TW8(tw_s, g * k1);
            R0 = make_double2(ar0 * tm.x - ai0 * tm.y, ar0 * tm.y + ai0 * tm.x);
        }
        {
            double2 tm = TW8(tw_s, (g + 8) * k1);
            R1 = make_double2(ar1 * tm.x - ai1 * tm.y, ar1 * tm.y + ai1 * tm.x);
        }
        {
            double2 tm = TW8(tw_s, (g + 16) * k1);
            R2 = make_double2(ar2 * tm.x - ai2 * tm.y, ar2 * tm.y + ai2 * tm.x);
        }
        {
            double2 tm = TW8(tw_s, (g + 24) * k1);
            R3 = make_double2(ar3 * tm.x - ai3 * tm.y, ar3 * tm.y + ai3 * tm.x);
        }
    }
    __syncthreads();   // xs reads done -> overwrite union with S

    uni[g * 32 + k1]        = R0;
    uni[(g + 8) * 32 + k1]  = R1;
    uni[(g + 16) * 32 + k1] = R2;
    uni[(g + 24) * 32 + k1] = R3;
    __syncthreads();

    // --- stage 2: bins k2 = g and g+8 via (-i)^t2 trick, one recurrence ---
    {
        const double2 wa = TW8(tw_s, 32 * g);   // e^{-2 pi i g/32}
        double ca = 1.0, sa = 0.0;
        double Ar = 0, Ai = 0, Br = 0, Bi = 0;
#pragma unroll
        for (int u = 0; u < 8; ++u) {
            {
                double2 S = uni[(4 * u + 0) * 32 + k1];
                double P = fma(S.x, ca, -(S.y * sa));
                double Q = fma(S.x, sa,  (S.y * ca));
                Ar += P; Ai += Q; Br += P; Bi += Q;
                double cn = fma(ca, wa.x, -(sa * wa.y));
                double sn = fma(sa, wa.x,  (ca * wa.y));
                ca = cn; sa = sn;
            }
            {
                double2 S = uni[(4 * u + 1) * 32 + k1];
                double P = fma(S.x, ca, -(S.y * sa));
                double Q = fma(S.x, sa,  (S.y * ca));
                Ar += P; Ai += Q; Br += Q; Bi -= P;
                double cn = fma(ca, wa.x, -(sa * wa.y));
                double sn = fma(sa, wa.x,  (ca * wa.y));
                ca = cn; sa = sn;
            }
            {
                double2 S = uni[(4 * u + 2) * 32 + k1];
                double P = fma(S.x, ca, -(S.y * sa));
                double Q = fma(S.x, sa,  (S.y * ca));
                Ar += P; Ai += Q; Br -= P; Bi -= Q;
                double cn = fma(ca, wa.x, -(sa * wa.y));
                double sn = fma(sa, wa.x,  (ca * wa.y));
                ca = cn; sa = sn;
            }
            {
                double2 S = uni[(4 * u + 3) * 32 + k1];
                double P = fma(S.x, ca, -(S.y * sa));
                double Q = fma(S.x, sa,  (S.y * ca));
                Ar += P; Ai += Q; Br -= Q; Bi += P;
                double cn = fma(ca, wa.x, -(sa * wa.y));
                double sn = fma(sa, wa.x,  (ca * wa.y));
                ca = cn; sa = sn;
            }
        }
        const int ka = k1 + 32 * g;          // == tid
        const int kb = k1 + 32 * (g + 8);    // == tid + 256
        const size_t base = (size_t)pair * 512;

        // amp^2 keys (ordering identical to amp; sqrt deferred to winners)
        double a2a = Ar * Ar + Ai * Ai;
        double a2b = Br * Br + Bi * Bi;
        unsigned long long bba = __double_as_longlong(a2a);
        unsigned long long bbb = __double_as_longlong(a2b);
        double keya = __longlong_as_double((bba & ~1023ULL) |
                                           (unsigned long long)(1023 - ka));
        double keyb = __longlong_as_double((bbb & ~1023ULL) |
                                           (unsigned long long)(1023 - kb));
        if (ka == 0) keya = -1.0;   // DC excluded
        keys[base + ka] = keya;
        keys[base + kb] = keyb;
        phase[base + ka] = __float2half(atan2f((float)Ai, (float)Ar));
        phase[base + kb] = __float2half(atan2f((float)Bi, (float)Br));
    }
}

// ---------------------------------------------------------------------------
// K2b: top-32 per pair, one WAVE per pair.
// sel = (amp, phi, k, cos(2 pi k/1024))
// ---------------------------------------------------------------------------
__global__ __launch_bounds__(256) void topk_kernel(const double* __restrict__ keys,
                                                   const __half* __restrict__ phase,
                                                   float4* __restrict__ sel) {
    const int tid  = threadIdx.x;
    const int lane = tid & 63;
    const int pair = blockIdx.x * 4 + (tid >> 6);
    const size_t base = (size_t)pair * 512;

    double kreg[8];
#pragma unroll
    for (int j = 0; j < 8; ++j) kreg[j] = keys[base + j * 64 + lane];

    double win = -2.0;
    for (int r = 0; r < 32; ++r) {
        double m01 = fmax(kreg[0], kreg[1]);
        double m23 = fmax(kreg[2], kreg[3]);
        double m45 = fmax(kreg[4], kreg[5]);
        double m67 = fmax(kreg[6], kreg[7]);
        double m = fmax(fmax(m01, m23), fmax(m45, m67));
#pragma unroll
        for (int off = 1; off < 64; off <<= 1)
            m = fmax(m, __shfl_xor(m, off));
#pragma unroll
        for (int j = 0; j < 8; ++j)
            if (kreg[j] == m) kreg[j] = -2.0;   // exact bit match (keys unique)
        if (lane == r) win = m;
    }

    if (lane < 32) {
        unsigned long long b = __double_as_longlong(win);
        int k = 1023 - (int)(b & 1023ULL);
        float ph = __half2float(phase[base + k]);
        double amp = sqrt(win);   // win = amp^2 (packed bits, rel err 2^-43)
        float aout = (float)(2.0 * amp / (1024.0 + 1e-8));
        const float C = 6.28318530717958647692f / 1024.0f;
        float tkc = __cosf((float)k * C);
        sel[(size_t)pair * 32 + lane] = make_float4(aout, ph, (float)k, tkc);
    }
}

// ---------------------------------------------------------------------------
// K2-fallback (monolithic dft+topk), used if ws too small
// ---------------------------------------------------------------------------
__global__ __launch_bounds__(256) void dft_topk_kernel(const float* __restrict__ xt,
                                                       const double2* __restrict__ twg,
                                                       float2* __restrict__ stats,
                                                       float4* __restrict__ sel) {
    __shared__ double  xs_s[1024];
    __shared__ double2 tw_s[1024];
    __shared__ double2 S_s[32][32];
    __shared__ double2 spec_s[512];
    __shared__ double  amp_s[512];
    __shared__ double  red_s[16];
    __shared__ double  bc_s[2];

    const int tid  = threadIdx.x;
    const int pair = blockIdx.x;
    const float4 v = reinterpret_cast<const float4*>(xt + (size_t)pair * T_IN)[tid];
#pragma unroll
    for (int i = 0; i < 4; ++i) tw_s[tid + 256 * i] = twg[tid + 256 * i];

    double sum = (double)v.x + (double)v.y + (double)v.z + (double)v.w;
    double sq  = (double)v.x * v.x + (double)v.y * v.y +
                 (double)v.z * v.z + (double)v.w * v.w;
#pragma unroll
    for (int off = 32; off; off >>= 1) {
        sum += __shfl_down(sum, off);
        sq  += __shfl_down(sq, off);
    }
    const int wv = tid >> 6;
    if ((tid & 63) == 0) { red_s[wv] = sum; red_s[8 + wv] = sq; }
    __syncthreads();
    if (tid == 0) {
        double s = red_s[0] + red_s[1] + red_s[2] + red_s[3];
        double q = red_s[8] + red_s[9] + red_s[10] + red_s[11];
        double mean = s * (1.0 / 1024.0);
        double var  = (q - 1024.0 * mean * mean) * (1.0 / 1023.0);
        var = var > 0.0 ? var : 0.0;
        double stdp = sqrt(var) + 1e-8;
        bc_s[0] = mean; bc_s[1] = stdp;
        stats[pair] = make_float2((float)mean, (float)stdp);
    }
    __syncthreads();
    const double mean = bc_s[0];
    const double inv  = 1.0 / bc_s[1];
    {
        double z0 = ((double)v.x - mean) * inv;
        double z1 = ((double)v.y - mean) * inv;
        double z2 = ((double)v.z - mean) * inv;
        double z3 = ((double)v.w - mean) * inv;
        z0 = fmin(2.0, fmax(-2.0, z0)) + 1e-9;
        z1 = fmin(2.0, fmax(-2.0, z1)) + 1e-9;
        z2 = fmin(2.0, fmax(-2.0, z2)) + 1e-9;
        z3 = fmin(2.0, fmax(-2.0, z3)) + 1e-9;
        xs_s[tid * 4 + 0] = z0; xs_s[tid * 4 + 1] = z1;
        xs_s[tid * 4 + 2] = z2; xs_s[tid * 4 + 3] = z3;
    }
    __syncthreads();
    const int k1 = tid & 31;
    const int g  = tid >> 5;
    {
        const double2 w = tw_s[k1 * 32];
        double c = 1.0, s = 0.0;
        double ar0 = 0, ai0 = 0, ar1 = 0, ai1 = 0;
        double ar2 = 0, ai2 = 0, ar3 = 0, ai3 = 0;
#pragma unroll 4
        for (int t1 = 0; t1 < 32; ++t1) {
            const double* xb = &xs_s[t1 * 32];
            double x0 = xb[g], x1 = xb[g + 8], x2 = xb[g + 16], x3 = xb[g + 24];
            ar0 = fma(x0, c, ar0); ai0 = fma(x0, s, ai0);
            ar1 = fma(x1, c, ar1); ai1 = fma(x1, s, ai1);
            ar2 = fma(x2, c, ar2); ai2 = fma(x2, s, ai2);
            ar3 = fma(x3, c, ar3); ai3 = fma(x3, s, ai3);
            double cn = c * w.x - s * w.y;
            double sn = s * w.x + c * w.y;
            c = cn; s = sn;
        }
        { double2 tm = tw_s[g * k1];
          S_s[g][k1] = make_double2(ar0 * tm.x - ai0 * tm.y, ar0 * tm.y + ai0 * tm.x); }
        { double2 tm = tw_s[(g + 8) * k1];
          S_s[g + 8][k1] = make_double2(ar1 * tm.x - ai1 * tm.y, ar1 * tm.y + ai1 * tm.x); }
        { double2 tm = tw_s[(g + 16) * k1];
          S_s[g + 16][k1] = make_double2(ar2 * tm.x - ai2 * tm.y, ar2 * tm.y + ai2 * tm.x); }
        { double2 tm = tw_s[(g + 24) * k1];
          S_s[g + 24][k1] = make_double2(ar3 * tm.x - ai3 * tm.y, ar3 * tm.y + ai3 * tm.x); }
    }
    __syncthreads();
    {
        const double2 wa = tw_s[32 * g];
        const double2 wb = tw_s[32 * (g + 8)];
        double ca = 1.0, sa = 0.0, cb = 1.0, sb = 0.0;
        double Ar = 0, Ai = 0, Br = 0, Bi = 0;
#pragma unroll 4
        for (int t2 = 0; t2 < 32; ++t2) {
            double2 S = S_s[t2][k1];
            Ar += S.x * ca - S.y * sa; Ai += S.x * sa + S.y * ca;
            Br += S.x * cb - S.y * sb; Bi += S.x * sb + S.y * cb;
            double cn = ca * wa.x - sa * wa.y;
            double sn = sa * wa.x + ca * wa.y;
            ca = cn; sa = sn;
            cn = cb * wb.x - sb * wb.y;
            sn = sb * wb.x + cb * wb.y;
            cb = cn; sb = sn;
        }
        const int ka = k1 + 32 * g;
        const int kb = k1 + 32 * (g + 8);
        spec_s[ka] = make_double2(Ar, Ai);
        amp_s[ka]  = (ka == 0) ? -1.0 : sqrt(Ar * Ar + Ai * Ai);
        spec_s[kb] = make_double2(Br, Bi);
        amp_s[kb]  = sqrt(Br * Br + Bi * Bi);
    }
    __syncthreads();
    if (tid < 64) {
        const int lane = tid;
        double a0 = amp_s[lane * 8 + 0], a1 = amp_s[lane * 8 + 1];
        double a2 = amp_s[lane * 8 + 2], a3 = amp_s[lane * 8 + 3];
        double a4 = amp_s[lane * 8 + 4], a5 = amp_s[lane * 8 + 5];
        double a6 = amp_s[lane * 8 + 6], a7 = amp_s[lane * 8 + 7];
        int my_sel = 0;
        for (int r = 0; r < 32; ++r) {
            double vmax = a0; int li = 0;
            if (a1 > vmax) { vmax = a1; li = 1; }
            if (a2 > vmax) { vmax = a2; li = 2; }
            if (a3 > vmax) { vmax = a3; li = 3; }
            if (a4 > vmax) { vmax = a4; li = 4; }
            if (a5 > vmax) { vmax = a5; li = 5; }
            if (a6 > vmax) { vmax = a6; li = 6; }
            if (a7 > vmax) { vmax = a7; li = 7; }
            int gi = lane * 8 + li;
#pragma unroll
            for (int off = 1; off < 64; off <<= 1) {
                double ov = __shfl_xor(vmax, off);
                int    og = __shfl_xor(gi, off);
                if (ov > vmax || (ov == vmax && og < gi)) { vmax = ov; gi = og; }
            }
            if ((gi >> 3) == lane) {
                switch (gi & 7) {
                    case 0: a0 = -2.0; break; case 1: a1 = -2.0; break;
                    case 2: a2 = -2.0; break; case 3: a3 = -2.0; break;
                    case 4: a4 = -2.0; break; case 5: a5 = -2.0; break;
                    case 6: a6 = -2.0; break; case 7: a7 = -2.0; break;
                }
            }
            if (lane == r) my_sel = gi;
        }
        if (lane < 32) {
            const int k = my_sel;
            double2 sp  = spec_s[k];
            double aout = 2.0 * amp_s[k] / (1024.0 + 1e-8);
            double ph   = atan2(sp.y, sp.x);
            const float C = 6.28318530717958647692f / 1024.0f;
            float tkc = __cosf((float)k * C);
            sel[(size_t)pair * 32 + lane] =
                make_float4((float)aout, (float)ph, (float)k, tkc);
        }
    }
}

// ---------------------------------------------------------------------------
// K3: rotation-based reconstruction, v5: NO LDS gathers.
// Per js: start (cos,sin) via one __sincosf(mm0*C + phi); step rotator from
// stored cos(kC) with sin = sqrt(1-c^2) (kC in (0,pi) -> sin >= 0); t5 = tk^5
// in registers. sel_s padded [32][65] to kill staging-write conflicts.
// ---------------------------------------------------------------------------
__global__ __launch_bounds__(256) void recon_kernel(const float4* __restrict__ sel,
                                                    const float2* __restrict__ stats,
                                                    float* __restrict__ out) {
    __shared__ float4 sel_s[32][65];
    __shared__ float2 st_s[64];
    const int bid   = blockIdx.x;
    const int chunk = bid & 31;
    const int dt    = (bid >> 5) & 7;
    const int b     = bid >> 8;
    const int d0    = dt * 64;
    const int tid   = threadIdx.x;
#pragma unroll
    for (int it = 0; it < 8; ++it) {
        int i   = tid + it * 256;
        int j   = i & 31;
        int dls = i >> 5;
        sel_s[j][dls] = sel[((size_t)(b * D_DIM + d0 + dls)) * 32 + j];
    }
    if (tid < 64) st_s[tid] = stats[b * D_DIM + d0 + tid];
    __syncthreads();

    const int dl    = tid & 63;
    const int wvv   = tid >> 6;
    const int tbase = chunk * 40 + wvv * 10;

    float acc[10];
#pragma unroll
    for (int j = 0; j < 10; ++j) acc[j] = 0.0f;

    const float C = 6.28318530717958647692f / 1024.0f;
#pragma unroll 2
    for (int js = 0; js < 32; ++js) {
        float4 tr = sel_s[js][dl];       // (a, phi, k, cos(kC))
        const float a = tr.x;
        int k = (int)tr.z;
        float tkc = tr.w;
        float tks = sqrtf(fmaxf(1.0f - tkc * tkc, 0.0f));   // kC in (0,pi)
        int mm0 = (k * tbase) & 1023;
        float ang0 = fmaf((float)mm0, C, tr.y);
        float sa, ca;
        __sincosf(ang0, &sa, &ca);
        // t5 = tk^5 via two squarings + mul
        float c2 = tkc * tkc - tks * tks, s2 = 2.0f * tkc * tks;
        float c4 = c2 * c2 - s2 * s2,     s4 = 2.0f * c2 * s2;
        float t5c = c4 * tkc - s4 * tks,  t5s = s4 * tkc + c4 * tks;
        float cb = ca * t5c - sa * t5s;
        float sb = sa * t5c + ca * t5s;
#pragma unroll
        for (int j = 0; j < 5; ++j) {
            acc[j]     = fmaf(a, ca, acc[j]);
            acc[j + 5] = fmaf(a, cb, acc[j + 5]);
            float can = ca * tkc - sa * tks;
            float san = sa * tkc + ca * tks;
            ca = can; sa = san;
            float cbn = cb * tkc - sb * tks;
            float sbn = sb * tkc + cb * tks;
            cb = cbn; sb = sbn;
        }
    }
    const float2 st = st_s[dl];
#pragma unroll
    for (int j = 0; j < 10; ++j) {
        out[((size_t)b * T_OUT + (tbase + j)) * D_DIM + d0 + dl] =
            fmaf(acc[j], st.y, st.x);
    }
}

// ---------------------------------------------------------------------------
extern "C" void kernel_launch(void* const* d_in, const int* in_sizes, int n_in,
                              void* d_out, int out_size, void* d_ws, size_t ws_size,
                              hipStream_t stream) {
    const float* x = (const float*)d_in[0];
    float* out = (float*)d_out;
    char* ws = (char*)d_ws;
    const size_t MB = 1024 * 1024;

    if (ws_size >= 39 * MB) {
        // split-path layout (total ~38.1 MB, no overlaps):
        float*   xt    = (float*)ws;                          // 16 MB  [0,16)
        double*  keys  = (double*)(ws + 16 * MB);             // 16 MB  [16,32)
        __half*  phase = (__half*)(ws + 32 * MB);             //  4 MB  [32,36)
        double2* tw    = (double2*)(ws + 36 * MB);            // 16 KB
        float2*  stats = (float2*)(ws + 36 * MB + 65536);     // 32 KB
        float4*  sel   = (float4*)(ws + 36 * MB + 131072);    //  2 MB

        transpose_kernel<<<dim3(8, 16, 8), 256, 0, stream>>>(x, xt, tw);
        dft_kernel<<<NPAIR, 256, 0, stream>>>(xt, tw, stats, keys, phase);
        topk_kernel<<<NPAIR / 4, 256, 0, stream>>>(keys, phase, sel);
        recon_kernel<<<2048, 256, 0, stream>>>(sel, stats, out);
    } else {
        // fallback
        float*   xt    = (float*)ws;                                    // 16 MB
        double2* tw    = (double2*)(ws + 16 * MB);                      // 16 KB
        float2*  stats = (float2*)(ws + 16 * MB + 16384);               // 32 KB
        float4*  sel   = (float4*)(ws + 16 * MB + 16384 + 32768);       //  2 MB

        transpose_kernel<<<dim3(8, 16, 8), 256, 0, stream>>>(x, xt, tw);
        dft_topk_kernel<<<NPAIR, 256, 0, stream>>>(xt, tw, stats, sel);
        recon_kernel<<<2048, 256, 0, stream>>>(sel, stats, out);
    }
}

// Round 10
// 88.545 us; speedup vs baseline: 1.3801x; 1.3496x over previous
//
#include <hip/hip_runtime.h>
#include <hip/hip_fp16.h>

#define T_IN 1024
#define D_DIM 512
#define T_OUT 1280
#define NPAIR 4096   // 8 * 512

// ---------------------------------------------------------------------------
// K1: transpose (b, t, d) -> (b, d, t), 64x64 LDS tiles.
// Also builds fp64 twiddles tw[m] = (cos, -sin)(2 pi m/1024), m=0..1023,
// in its first 4 (x,0,0) blocks.
// ---------------------------------------------------------------------------
__global__ __launch_bounds__(256) void transpose_kernel(const float* __restrict__ x,
                                                        float* __restrict__ xt,
                                                        double2* __restrict__ tw) {
    __shared__ float tile[64][65];
    const int b  = blockIdx.z;
    const int t0 = blockIdx.y * 64;
    const int d0 = blockIdx.x * 64;
    const int dl = threadIdx.x & 63;
    const int r0 = threadIdx.x >> 6;   // 0..3

    if (blockIdx.x < 4 && blockIdx.y == 0 && blockIdx.z == 0) {
        int m = blockIdx.x * 256 + threadIdx.x;
        double th = (6.283185307179586476925286766559 / 1024.0) * (double)m;
        tw[m] = make_double2(cos(th), -sin(th));
    }

#pragma unroll
    for (int i = 0; i < 16; ++i) {
        int tl = r0 * 16 + i;
        tile[tl][dl] = x[((size_t)b * T_IN + (t0 + tl)) * D_DIM + d0 + dl];
    }
    __syncthreads();
#pragma unroll
    for (int i = 0; i < 16; ++i) {
        int dl2 = r0 * 16 + i;
        xt[((size_t)b * D_DIM + (d0 + dl2)) * T_IN + t0 + dl] = tile[dl][dl2];
    }
}

// ---------------------------------------------------------------------------
// eighth-table twiddle lookup: e^{-2 pi i m/1024}, m in [0, 1024)
// ---------------------------------------------------------------------------
__device__ __forceinline__ double2 TW8(const double2* __restrict__ E, int m) {
    int r = m & 255;
    int q = (m >> 8) & 3;
    double c, s;
    if (r <= 128) { double2 t = E[r];       c = t.x; s = t.y; }
    else          { double2 t = E[256 - r]; c = t.y; s = t.x; }
    double C, S;
    switch (q) {
        case 0:  C = c;  S = s;  break;
        case 1:  C = -s; S = c;  break;
        case 2:  C = -c; S = -s; break;
        default: C = s;  S = -c; break;
    }
    return make_double2(C, -S);
}

// ---------------------------------------------------------------------------
// K2: per (b,d): stats -> standardize/clip -> even/odd butterfly -> 1024-pt
// real DFT (32x32 Cooley-Tukey, fp64) -> fp64 amp^2 sort-keys + half phase.
// ---------------------------------------------------------------------------
__global__ __launch_bounds__(256) void dft_kernel(const float* __restrict__ xt,
                                                  const double2* __restrict__ twg,
                                                  float2* __restrict__ stats,
                                                  double* __restrict__ keys,
                                                  __half* __restrict__ phase) {
    __shared__ double2 uni[1024];       // phase A: xs (1024 dbl); phase B: S[32][32]
    __shared__ double2 tw_s[130];       // eighth table E[0..128]
    __shared__ double  red_s[16];
    double* xs_s = (double*)uni;

    const int tid  = threadIdx.x;
    const int pair = blockIdx.x;

    const float4 v = reinterpret_cast<const float4*>(xt + (size_t)pair * T_IN)[tid];

    if (tid < 130) {
        double2 t = twg[tid];                 // (cos, -sin)
        tw_s[tid] = make_double2(t.x, -t.y);  // store (cos, +sin)
    }

    // --- stats (fp64, deterministic tree reduce; final sum redundant per-thread) ---
    double sum = (double)v.x + (double)v.y + (double)v.z + (double)v.w;
    double sq  = (double)v.x * v.x + (double)v.y * v.y +
                 (double)v.z * v.z + (double)v.w * v.w;
#pragma unroll
    for (int off = 32; off; off >>= 1) {
        sum += __shfl_down(sum, off);
        sq  += __shfl_down(sq, off);
    }
    const int wv = tid >> 6;
    if ((tid & 63) == 0) { red_s[wv] = sum; red_s[8 + wv] = sq; }
    __syncthreads();
    double mean, stdp;
    {
        double s = red_s[0] + red_s[1] + red_s[2] + red_s[3];
        double q = red_s[8] + red_s[9] + red_s[10] + red_s[11];
        mean = s * (1.0 / 1024.0);
        double var = (q - 1024.0 * mean * mean) * (1.0 / 1023.0);
        var = var > 0.0 ? var : 0.0;
        stdp = sqrt(var) + 1e-8;   // reference: std + 1e-8
        if (tid == 0) stats[pair] = make_float2((float)mean, (float)stdp);
    }
    const double inv = 1.0 / stdp;
    {
        double z0 = ((double)v.x - mean) * inv;
        double z1 = ((double)v.y - mean) * inv;
        double z2 = ((double)v.z - mean) * inv;
        double z3 = ((double)v.w - mean) * inv;
        z0 = fmin(2.0, fmax(-2.0, z0)) + 1e-9;
        z1 = fmin(2.0, fmax(-2.0, z1)) + 1e-9;
        z2 = fmin(2.0, fmax(-2.0, z2)) + 1e-9;
        z3 = fmin(2.0, fmax(-2.0, z3)) + 1e-9;
        xs_s[tid * 4 + 0] = z0;
        xs_s[tid * 4 + 1] = z1;
        xs_s[tid * 4 + 2] = z2;
        xs_s[tid * 4 + 3] = z3;
    }
    __syncthreads();

    // --- in-place even/odd butterfly over t1 (pairs t1 <-> 32-t1, t1=1..15) ---
    {
        int idx = tid;
#pragma unroll
        for (int rr = 0; rr < 2; ++rr) {
            if (idx < 480) {
                int t1p = 1 + (idx >> 5);
                int t2c = idx & 31;
                int ia = t1p * 32 + t2c;
                int ib = (32 - t1p) * 32 + t2c;
                double a = xs_s[ia], b = xs_s[ib];
                xs_s[ia] = a + b;
                xs_s[ib] = a - b;
            }
            idx += 256;
        }
    }
    __syncthreads();

    const int k1 = tid & 31;
    const int g  = tid >> 5;   // 0..7

    // --- stage 1 (into registers) ---
    double2 R0, R1, R2, R3;
    {
        const double2 w = TW8(tw_s, k1 * 32);   // e^{-2 pi i k1/32}
        const double sgn16 = (k1 & 1) ? -1.0 : 1.0;

        double ar0 = xs_s[g]      + sgn16 * xs_s[512 + g];
        double ar1 = xs_s[g + 8]  + sgn16 * xs_s[512 + g + 8];
        double ar2 = xs_s[g + 16] + sgn16 * xs_s[512 + g + 16];
        double ar3 = xs_s[g + 24] + sgn16 * xs_s[512 + g + 24];
        double ai0 = 0, ai1 = 0, ai2 = 0, ai3 = 0;

        double c = w.x, s = w.y;   // t1 = 1
#pragma unroll 5
        for (int t1 = 1; t1 <= 15; ++t1) {
            const double* eb = &xs_s[t1 * 32];
            const double* ob = &xs_s[(32 - t1) * 32];
            ar0 = fma(eb[g], c, ar0);      ai0 = fma(ob[g], s, ai0);
            ar1 = fma(eb[g + 8], c, ar1);  ai1 = fma(ob[g + 8], s, ai1);
            ar2 = fma(eb[g + 16], c, ar2); ai2 = fma(ob[g + 16], s, ai2);
            ar3 = fma(eb[g + 24], c, ar3); ai3 = fma(ob[g + 24], s, ai3);
            double cn = c * w.x - s * w.y;
            double sn = s * w.x + c * w.y;
            c = cn; s = sn;
        }
        {
            double2 tm = TW8(tw_s, g * k1);
            R0 = make_double2(ar0 * tm.x - ai0 * tm.y, ar0 * tm.y + ai0 * tm.x);
        }
        {
            double2 tm = TW8(tw_s, (g + 8) * k1);
            R1 = make_double2(ar1 * tm.x - ai1 * tm.y, ar1 * tm.y + ai1 * tm.x);
        }
        {
            double2 tm = TW8(tw_s, (g + 16) * k1);
            R2 = make_double2(ar2 * tm.x - ai2 * tm.y, ar2 * tm.y + ai2 * tm.x);
        }
        {
            double2 tm = TW8(tw_s, (g + 24) * k1);
            R3 = make_double2(ar3 * tm.x - ai3 * tm.y, ar3 * tm.y + ai3 * tm.x);
        }
    }
    __syncthreads();   // xs reads done -> overwrite union with S

    uni[g * 32 + k1]        = R0;
    uni[(g + 8) * 32 + k1]  = R1;
    uni[(g + 16) * 32 + k1] = R2;
    uni[(g + 24) * 32 + k1] = R3;
    __syncthreads();

    // --- stage 2: bins k2 = g and g+8 via (-i)^t2 trick, one recurrence ---
    {
        const double2 wa = TW8(tw_s, 32 * g);   // e^{-2 pi i g/32}
        double ca = 1.0, sa = 0.0;
        double Ar = 0, Ai = 0, Br = 0, Bi = 0;
#pragma unroll
        for (int u = 0; u < 8; ++u) {
            {
                double2 S = uni[(4 * u + 0) * 32 + k1];
                double P = fma(S.x, ca, -(S.y * sa));
                double Q = fma(S.x, sa,  (S.y * ca));
                Ar += P; Ai += Q; Br += P; Bi += Q;
                double cn = fma(ca, wa.x, -(sa * wa.y));
                double sn = fma(sa, wa.x,  (ca * wa.y));
                ca = cn; sa = sn;
            }
            {
                double2 S = uni[(4 * u + 1) * 32 + k1];
                double P = fma(S.x, ca, -(S.y * sa));
                double Q = fma(S.x, sa,  (S.y * ca));
                Ar += P; Ai += Q; Br += Q; Bi -= P;
                double cn = fma(ca, wa.x, -(sa * wa.y));
                double sn = fma(sa, wa.x,  (ca * wa.y));
                ca = cn; sa = sn;
            }
            {
                double2 S = uni[(4 * u + 2) * 32 + k1];
                double P = fma(S.x, ca, -(S.y * sa));
                double Q = fma(S.x, sa,  (S.y * ca));
                Ar += P; Ai += Q; Br -= P; Bi -= Q;
                double cn = fma(ca, wa.x, -(sa * wa.y));
                double sn = fma(sa, wa.x,  (ca * wa.y));
                ca = cn; sa = sn;
            }
            {
                double2 S = uni[(4 * u + 3) * 32 + k1];
                double P = fma(S.x, ca, -(S.y * sa));
                double Q = fma(S.x, sa,  (S.y * ca));
                Ar += P; Ai += Q; Br -= Q; Bi += P;
                double cn = fma(ca, wa.x, -(sa * wa.y));
                double sn = fma(sa, wa.x,  (ca * wa.y));
                ca = cn; sa = sn;
            }
        }
        const int ka = k1 + 32 * g;          // == tid
        const int kb = k1 + 32 * (g + 8);    // == tid + 256
        const size_t base = (size_t)pair * 512;

        // amp^2 keys (ordering identical to amp; sqrt deferred to winners)
        double a2a = Ar * Ar + Ai * Ai;
        double a2b = Br * Br + Bi * Bi;
        unsigned long long bba = __double_as_longlong(a2a);
        unsigned long long bbb = __double_as_longlong(a2b);
        double keya = __longlong_as_double((bba & ~1023ULL) |
                                           (unsigned long long)(1023 - ka));
        double keyb = __longlong_as_double((bbb & ~1023ULL) |
                                           (unsigned long long)(1023 - kb));
        if (ka == 0) keya = -1.0;   // DC excluded
        keys[base + ka] = keya;
        keys[base + kb] = keyb;
        phase[base + ka] = __float2half(atan2f((float)Ai, (float)Ar));
        phase[base + kb] = __float2half(atan2f((float)Bi, (float)Br));
    }
}

// ---------------------------------------------------------------------------
// K2b: top-32 per pair, one WAVE per pair.
// sel = (amp, phi, k, cos(2 pi k/1024))
// ---------------------------------------------------------------------------
__global__ __launch_bounds__(256) void topk_kernel(const double* __restrict__ keys,
                                                   const __half* __restrict__ phase,
                                                   float4* __restrict__ sel) {
    const int tid  = threadIdx.x;
    const int lane = tid & 63;
    const int pair = blockIdx.x * 4 + (tid >> 6);
    const size_t base = (size_t)pair * 512;

    double kreg[8];
#pragma unroll
    for (int j = 0; j < 8; ++j) kreg[j] = keys[base + j * 64 + lane];

    double win = -2.0;
    for (int r = 0; r < 32; ++r) {
        double m01 = fmax(kreg[0], kreg[1]);
        double m23 = fmax(kreg[2], kreg[3]);
        double m45 = fmax(kreg[4], kreg[5]);
        double m67 = fmax(kreg[6], kreg[7]);
        double m = fmax(fmax(m01, m23), fmax(m45, m67));
#pragma unroll
        for (int off = 1; off < 64; off <<= 1)
            m = fmax(m, __shfl_xor(m, off));
#pragma unroll
        for (int j = 0; j < 8; ++j)
            if (kreg[j] == m) kreg[j] = -2.0;   // exact bit match (keys unique)
        if (lane == r) win = m;
    }

    if (lane < 32) {
        unsigned long long b = __double_as_longlong(win);
        int k = 1023 - (int)(b & 1023ULL);
        float ph = __half2float(phase[base + k]);
        double amp = sqrt(win);   // win = amp^2 (packed bits, rel err 2^-43)
        float aout = (float)(2.0 * amp / (1024.0 + 1e-8));
        const float C = 6.28318530717958647692f / 1024.0f;
        float tkc = __cosf((float)k * C);
        sel[(size_t)pair * 32 + lane] = make_float4(aout, ph, (float)k, tkc);
    }
}

// ---------------------------------------------------------------------------
// K2-fallback (monolithic dft+topk), used if ws too small
// ---------------------------------------------------------------------------
__global__ __launch_bounds__(256) void dft_topk_kernel(const float* __restrict__ xt,
                                                       const double2* __restrict__ twg,
                                                       float2* __restrict__ stats,
                                                       float4* __restrict__ sel) {
    __shared__ double  xs_s[1024];
    __shared__ double2 tw_s[1024];
    __shared__ double2 S_s[32][32];
    __shared__ double2 spec_s[512];
    __shared__ double  amp_s[512];
    __shared__ double  red_s[16];
    __shared__ double  bc_s[2];

    const int tid  = threadIdx.x;
    const int pair = blockIdx.x;
    const float4 v = reinterpret_cast<const float4*>(xt + (size_t)pair * T_IN)[tid];
#pragma unroll
    for (int i = 0; i < 4; ++i) tw_s[tid + 256 * i] = twg[tid + 256 * i];

    double sum = (double)v.x + (double)v.y + (double)v.z + (double)v.w;
    double sq  = (double)v.x * v.x + (double)v.y * v.y +
                 (double)v.z * v.z + (double)v.w * v.w;
#pragma unroll
    for (int off = 32; off; off >>= 1) {
        sum += __shfl_down(sum, off);
        sq  += __shfl_down(sq, off);
    }
    const int wv = tid >> 6;
    if ((tid & 63) == 0) { red_s[wv] = sum; red_s[8 + wv] = sq; }
    __syncthreads();
    if (tid == 0) {
        double s = red_s[0] + red_s[1] + red_s[2] + red_s[3];
        double q = red_s[8] + red_s[9] + red_s[10] + red_s[11];
        double mean = s * (1.0 / 1024.0);
        double var  = (q - 1024.0 * mean * mean) * (1.0 / 1023.0);
        var = var > 0.0 ? var : 0.0;
        double stdp = sqrt(var) + 1e-8;
        bc_s[0] = mean; bc_s[1] = stdp;
        stats[pair] = make_float2((float)mean, (float)stdp);
    }
    __syncthreads();
    const double mean = bc_s[0];
    const double inv  = 1.0 / bc_s[1];
    {
        double z0 = ((double)v.x - mean) * inv;
        double z1 = ((double)v.y - mean) * inv;
        double z2 = ((double)v.z - mean) * inv;
        double z3 = ((double)v.w - mean) * inv;
        z0 = fmin(2.0, fmax(-2.0, z0)) + 1e-9;
        z1 = fmin(2.0, fmax(-2.0, z1)) + 1e-9;
        z2 = fmin(2.0, fmax(-2.0, z2)) + 1e-9;
        z3 = fmin(2.0, fmax(-2.0, z3)) + 1e-9;
        xs_s[tid * 4 + 0] = z0; xs_s[tid * 4 + 1] = z1;
        xs_s[tid * 4 + 2] = z2; xs_s[tid * 4 + 3] = z3;
    }
    __syncthreads();
    const int k1 = tid & 31;
    const int g  = tid >> 5;
    {
        const double2 w = tw_s[k1 * 32];
        double c = 1.0, s = 0.0;
        double ar0 = 0, ai0 = 0, ar1 = 0, ai1 = 0;
        double ar2 = 0, ai2 = 0, ar3 = 0, ai3 = 0;
#pragma unroll 4
        for (int t1 = 0; t1 < 32; ++t1) {
            const double* xb = &xs_s[t1 * 32];
            double x0 = xb[g], x1 = xb[g + 8], x2 = xb[g + 16], x3 = xb[g + 24];
            ar0 = fma(x0, c, ar0); ai0 = fma(x0, s, ai0);
            ar1 = fma(x1, c, ar1); ai1 = fma(x1, s, ai1);
            ar2 = fma(x2, c, ar2); ai2 = fma(x2, s, ai2);
            ar3 = fma(x3, c, ar3); ai3 = fma(x3, s, ai3);
            double cn = c * w.x - s * w.y;
            double sn = s * w.x + c * w.y;
            c = cn; s = sn;
        }
        { double2 tm = tw_s[g * k1];
          S_s[g][k1] = make_double2(ar0 * tm.x - ai0 * tm.y, ar0 * tm.y + ai0 * tm.x); }
        { double2 tm = tw_s[(g + 8) * k1];
          S_s[g + 8][k1] = make_double2(ar1 * tm.x - ai1 * tm.y, ar1 * tm.y + ai1 * tm.x); }
        { double2 tm = tw_s[(g + 16) * k1];
          S_s[g + 16][k1] = make_double2(ar2 * tm.x - ai2 * tm.y, ar2 * tm.y + ai2 * tm.x); }
        { double2 tm = tw_s[(g + 24) * k1];
          S_s[g + 24][k1] = make_double2(ar3 * tm.x - ai3 * tm.y, ar3 * tm.y + ai3 * tm.x); }
    }
    __syncthreads();
    {
        const double2 wa = tw_s[32 * g];
        const double2 wb = tw_s[32 * (g + 8)];
        double ca = 1.0, sa = 0.0, cb = 1.0, sb = 0.0;
        double Ar = 0, Ai = 0, Br = 0, Bi = 0;
#pragma unroll 4
        for (int t2 = 0; t2 < 32; ++t2) {
            double2 S = S_s[t2][k1];
            Ar += S.x * ca - S.y * sa; Ai += S.x * sa + S.y * ca;
            Br += S.x * cb - S.y * sb; Bi += S.x * sb + S.y * cb;
            double cn = ca * wa.x - sa * wa.y;
            double sn = sa * wa.x + ca * wa.y;
            ca = cn; sa = sn;
            cn = cb * wb.x - sb * wb.y;
            sn = sb * wb.x + cb * wb.y;
            cb = cn; sb = sn;
        }
        const int ka = k1 + 32 * g;
        const int kb = k1 + 32 * (g + 8);
        spec_s[ka] = make_double2(Ar, Ai);
        amp_s[ka]  = (ka == 0) ? -1.0 : sqrt(Ar * Ar + Ai * Ai);
        spec_s[kb] = make_double2(Br, Bi);
        amp_s[kb]  = sqrt(Br * Br + Bi * Bi);
    }
    __syncthreads();
    if (tid < 64) {
        const int lane = tid;
        double a0 = amp_s[lane * 8 + 0], a1 = amp_s[lane * 8 + 1];
        double a2 = amp_s[lane * 8 + 2], a3 = amp_s[lane * 8 + 3];
        double a4 = amp_s[lane * 8 + 4], a5 = amp_s[lane * 8 + 5];
        double a6 = amp_s[lane * 8 + 6], a7 = amp_s[lane * 8 + 7];
        int my_sel = 0;
        for (int r = 0; r < 32; ++r) {
            double vmax = a0; int li = 0;
            if (a1 > vmax) { vmax = a1; li = 1; }
            if (a2 > vmax) { vmax = a2; li = 2; }
            if (a3 > vmax) { vmax = a3; li = 3; }
            if (a4 > vmax) { vmax = a4; li = 4; }
            if (a5 > vmax) { vmax = a5; li = 5; }
            if (a6 > vmax) { vmax = a6; li = 6; }
            if (a7 > vmax) { vmax = a7; li = 7; }
            int gi = lane * 8 + li;
#pragma unroll
            for (int off = 1; off < 64; off <<= 1) {
                double ov = __shfl_xor(vmax, off);
                int    og = __shfl_xor(gi, off);
                if (ov > vmax || (ov == vmax && og < gi)) { vmax = ov; gi = og; }
            }
            if ((gi >> 3) == lane) {
                switch (gi & 7) {
                    case 0: a0 = -2.0; break; case 1: a1 = -2.0; break;
                    case 2: a2 = -2.0; break; case 3: a3 = -2.0; break;
                    case 4: a4 = -2.0; break; case 5: a5 = -2.0; break;
                    case 6: a6 = -2.0; break; case 7: a7 = -2.0; break;
                }
            }
            if (lane == r) my_sel = gi;
        }
        if (lane < 32) {
            const int k = my_sel;
            double2 sp  = spec_s[k];
            double aout = 2.0 * amp_s[k] / (1024.0 + 1e-8);
            double ph   = atan2(sp.y, sp.x);
            const float C = 6.28318530717958647692f / 1024.0f;
            float tkc = __cosf((float)k * C);
            sel[(size_t)pair * 32 + lane] =
                make_float4((float)aout, (float)ph, (float)k, tkc);
        }
    }
}

// ---------------------------------------------------------------------------
// K3 v6: Chebyshev reconstruction + t-periodicity.
// cos(ang0 + n*kC) via c_{n+1} = 2cos(kC)*c_n - c_{n-1}: 2 fma/term.
// out[t+1024] = out[t] for t<256 (angle periodic mod 2pi, exact).
// Block: 64 d-lanes x 4 waves x 16 t; 16 chunks of 64 t cover t<1024.
// ---------------------------------------------------------------------------
__global__ __launch_bounds__(256) void recon_kernel(const float4* __restrict__ sel,
                                                    const float2* __restrict__ stats,
                                                    float* __restrict__ out) {
    __shared__ float4 sel_s[32][65];
    __shared__ float2 st_s[64];
    const int bid   = blockIdx.x;
    const int chunk = bid & 15;        // 16 chunks x 64 t
    const int dt    = (bid >> 4) & 7;
    const int b     = bid >> 7;
    const int d0    = dt * 64;
    const int tid   = threadIdx.x;
#pragma unroll
    for (int it = 0; it < 8; ++it) {
        int i   = tid + it * 256;
        int j   = i & 31;
        int dls = i >> 5;
        sel_s[j][dls] = sel[((size_t)(b * D_DIM + d0 + dls)) * 32 + j];
    }
    if (tid < 64) st_s[tid] = stats[b * D_DIM + d0 + tid];
    __syncthreads();

    const int dl    = tid & 63;
    const int wvv   = tid >> 6;
    const int tbase = chunk * 64 + wvv * 16;   // < 1024

    float acc[16];
#pragma unroll
    for (int j = 0; j < 16; ++j) acc[j] = 0.0f;

    const float C = 6.28318530717958647692f / 1024.0f;
#pragma unroll 2
    for (int js = 0; js < 32; ++js) {
        float4 tr = sel_s[js][dl];       // (a, phi, k, cos(kC))
        const float a = tr.x;
        int k = (int)tr.z;
        float ck = tr.w;
        float sk = sqrtf(fmaxf(1.0f - ck * ck, 0.0f));   // k in [1,511] -> sin>0
        int mm0 = (k * tbase) & 1023;
        float ang0 = fmaf((float)mm0, C, tr.y);
        float s0, c0;
        __sincosf(ang0, &s0, &c0);
        float c1 = c0 * ck - s0 * sk;
        float K2 = ck + ck;
        acc[0] = fmaf(a, c0, acc[0]);
        acc[1] = fmaf(a, c1, acc[1]);
#pragma unroll
        for (int j = 2; j < 16; ++j) {
            float c2 = fmaf(K2, c1, -c0);
            acc[j] = fmaf(a, c2, acc[j]);
            c0 = c1; c1 = c2;
        }
    }
    const float2 st = st_s[dl];
#pragma unroll
    for (int j = 0; j < 16; ++j) {
        float o = fmaf(acc[j], st.y, st.x);
        int t = tbase + j;
        out[((size_t)b * T_OUT + t) * D_DIM + d0 + dl] = o;
        if (t < 256)
            out[((size_t)b * T_OUT + t + 1024) * D_DIM + d0 + dl] = o;
    }
}

// ---------------------------------------------------------------------------
extern "C" void kernel_launch(void* const* d_in, const int* in_sizes, int n_in,
                              void* d_out, int out_size, void* d_ws, size_t ws_size,
                              hipStream_t stream) {
    const float* x = (const float*)d_in[0];
    float* out = (float*)d_out;
    char* ws = (char*)d_ws;
    const size_t MB = 1024 * 1024;

    if (ws_size >= 39 * MB) {
        // split-path layout (total ~38.1 MB, no overlaps):
        float*   xt    = (float*)ws;                          // 16 MB  [0,16)
        double*  keys  = (double*)(ws + 16 * MB);             // 16 MB  [16,32)
        __half*  phase = (__half*)(ws + 32 * MB);             //  4 MB  [32,36)
        double2* tw    = (double2*)(ws + 36 * MB);            // 16 KB
        float2*  stats = (float2*)(ws + 36 * MB + 65536);     // 32 KB
        float4*  sel   = (float4*)(ws + 36 * MB + 131072);    //  2 MB

        transpose_kernel<<<dim3(8, 16, 8), 256, 0, stream>>>(x, xt, tw);
        dft_kernel<<<NPAIR, 256, 0, stream>>>(xt, tw, stats, keys, phase);
        topk_kernel<<<NPAIR / 4, 256, 0, stream>>>(keys, phase, sel);
        recon_kernel<<<1024, 256, 0, stream>>>(sel, stats, out);
    } else {
        // fallback
        float*   xt    = (float*)ws;                                    // 16 MB
        double2* tw    = (double2*)(ws + 16 * MB);                      // 16 KB
        float2*  stats = (float2*)(ws + 16 * MB + 16384);               // 32 KB
        float4*  sel   = (float4*)(ws + 16 * MB + 16384 + 32768);       //  2 MB

        transpose_kernel<<<dim3(8, 16, 8), 256, 0, stream>>>(x, xt, tw);
        dft_topk_kernel<<<NPAIR, 256, 0, stream>>>(xt, tw, stats, sel);
        recon_kernel<<<1024, 256, 0, stream>>>(sel, stats, out);
    }
}

// Round 11
// 86.747 us; speedup vs baseline: 1.4087x; 1.0207x over previous
//
#include <hip/hip_runtime.h>
#include <hip/hip_fp16.h>

#define T_IN 1024
#define D_DIM 512
#define T_OUT 1280
#define NPAIR 4096   // 8 * 512

// ---------------------------------------------------------------------------
// K1: transpose (b, t, d) -> (b, d, t), 64x64 LDS tiles.
// Also builds fp64 twiddles tw[m] = (cos, -sin)(2 pi m/1024), m=0..1023,
// in its first 4 (x,0,0) blocks.
// ---------------------------------------------------------------------------
__global__ __launch_bounds__(256) void transpose_kernel(const float* __restrict__ x,
                                                        float* __restrict__ xt,
                                                        double2* __restrict__ tw) {
    __shared__ float tile[64][65];
    const int b  = blockIdx.z;
    const int t0 = blockIdx.y * 64;
    const int d0 = blockIdx.x * 64;
    const int dl = threadIdx.x & 63;
    const int r0 = threadIdx.x >> 6;   // 0..3

    if (blockIdx.x < 4 && blockIdx.y == 0 && blockIdx.z == 0) {
        int m = blockIdx.x * 256 + threadIdx.x;
        double th = (6.283185307179586476925286766559 / 1024.0) * (double)m;
        tw[m] = make_double2(cos(th), -sin(th));
    }

#pragma unroll
    for (int i = 0; i < 16; ++i) {
        int tl = r0 * 16 + i;
        tile[tl][dl] = x[((size_t)b * T_IN + (t0 + tl)) * D_DIM + d0 + dl];
    }
    __syncthreads();
#pragma unroll
    for (int i = 0; i < 16; ++i) {
        int dl2 = r0 * 16 + i;
        xt[((size_t)b * D_DIM + (d0 + dl2)) * T_IN + t0 + dl] = tile[dl][dl2];
    }
}

// ---------------------------------------------------------------------------
// eighth-table twiddle lookup: e^{-2 pi i m/1024}, m in [0, 1024)
// ---------------------------------------------------------------------------
__device__ __forceinline__ double2 TW8(const double2* __restrict__ E, int m) {
    int r = m & 255;
    int q = (m >> 8) & 3;
    double c, s;
    if (r <= 128) { double2 t = E[r];       c = t.x; s = t.y; }
    else          { double2 t = E[256 - r]; c = t.y; s = t.x; }
    double C, S;
    switch (q) {
        case 0:  C = c;  S = s;  break;
        case 1:  C = -s; S = c;  break;
        case 2:  C = -c; S = -s; break;
        default: C = s;  S = -c; break;
    }
    return make_double2(C, -S);
}

// ---------------------------------------------------------------------------
// K2: per (b,d): stats -> standardize/clip -> even/odd butterfly -> 1024-pt
// real DFT (32x32 Cooley-Tukey, fp64) -> fp64 amp^2 sort-keys + half phase.
// Stage 2 uses the t2<->t2+16 fold: both bins (g, g+8) share parity, so
// E[t2] = S[t2] + (-1)^g S[t2+16] feeds both via the (-i)^t2 trick.
// ---------------------------------------------------------------------------
__global__ __launch_bounds__(256) void dft_kernel(const float* __restrict__ xt,
                                                  const double2* __restrict__ twg,
                                                  float2* __restrict__ stats,
                                                  double* __restrict__ keys,
                                                  __half* __restrict__ phase) {
    __shared__ double2 uni[1024];       // phase A: xs (1024 dbl); phase B: S[32][32]
    __shared__ double2 tw_s[130];       // eighth table E[0..128]
    __shared__ double  red_s[16];
    double* xs_s = (double*)uni;

    const int tid  = threadIdx.x;
    const int pair = blockIdx.x;

    const float4 v = reinterpret_cast<const float4*>(xt + (size_t)pair * T_IN)[tid];

    if (tid < 130) {
        double2 t = twg[tid];                 // (cos, -sin)
        tw_s[tid] = make_double2(t.x, -t.y);  // store (cos, +sin)
    }

    // --- stats (fp64, deterministic tree reduce; final sum redundant per-thread) ---
    double sum = (double)v.x + (double)v.y + (double)v.z + (double)v.w;
    double sq  = (double)v.x * v.x + (double)v.y * v.y +
                 (double)v.z * v.z + (double)v.w * v.w;
#pragma unroll
    for (int off = 32; off; off >>= 1) {
        sum += __shfl_down(sum, off);
        sq  += __shfl_down(sq, off);
    }
    const int wv = tid >> 6;
    if ((tid & 63) == 0) { red_s[wv] = sum; red_s[8 + wv] = sq; }
    __syncthreads();
    double mean, stdp;
    {
        double s = red_s[0] + red_s[1] + red_s[2] + red_s[3];
        double q = red_s[8] + red_s[9] + red_s[10] + red_s[11];
        mean = s * (1.0 / 1024.0);
        double var = (q - 1024.0 * mean * mean) * (1.0 / 1023.0);
        var = var > 0.0 ? var : 0.0;
        stdp = sqrt(var) + 1e-8;   // reference: std + 1e-8
        if (tid == 0) stats[pair] = make_float2((float)mean, (float)stdp);
    }
    const double inv = 1.0 / stdp;
    {
        double z0 = ((double)v.x - mean) * inv;
        double z1 = ((double)v.y - mean) * inv;
        double z2 = ((double)v.z - mean) * inv;
        double z3 = ((double)v.w - mean) * inv;
        z0 = fmin(2.0, fmax(-2.0, z0)) + 1e-9;
        z1 = fmin(2.0, fmax(-2.0, z1)) + 1e-9;
        z2 = fmin(2.0, fmax(-2.0, z2)) + 1e-9;
        z3 = fmin(2.0, fmax(-2.0, z3)) + 1e-9;
        xs_s[tid * 4 + 0] = z0;
        xs_s[tid * 4 + 1] = z1;
        xs_s[tid * 4 + 2] = z2;
        xs_s[tid * 4 + 3] = z3;
    }
    __syncthreads();

    // --- in-place even/odd butterfly over t1 (pairs t1 <-> 32-t1, t1=1..15) ---
    {
        int idx = tid;
#pragma unroll
        for (int rr = 0; rr < 2; ++rr) {
            if (idx < 480) {
                int t1p = 1 + (idx >> 5);
                int t2c = idx & 31;
                int ia = t1p * 32 + t2c;
                int ib = (32 - t1p) * 32 + t2c;
                double a = xs_s[ia], b = xs_s[ib];
                xs_s[ia] = a + b;
                xs_s[ib] = a - b;
            }
            idx += 256;
        }
    }
    __syncthreads();

    const int k1 = tid & 31;
    const int g  = tid >> 5;   // 0..7

    // --- stage 1 (into registers) ---
    double2 R0, R1, R2, R3;
    {
        const double2 w = TW8(tw_s, k1 * 32);   // e^{-2 pi i k1/32}
        const double sgn16 = (k1 & 1) ? -1.0 : 1.0;

        double ar0 = xs_s[g]      + sgn16 * xs_s[512 + g];
        double ar1 = xs_s[g + 8]  + sgn16 * xs_s[512 + g + 8];
        double ar2 = xs_s[g + 16] + sgn16 * xs_s[512 + g + 16];
        double ar3 = xs_s[g + 24] + sgn16 * xs_s[512 + g + 24];
        double ai0 = 0, ai1 = 0, ai2 = 0, ai3 = 0;

        double c = w.x, s = w.y;   // t1 = 1
#pragma unroll 5
        for (int t1 = 1; t1 <= 15; ++t1) {
            const double* eb = &xs_s[t1 * 32];
            const double* ob = &xs_s[(32 - t1) * 32];
            ar0 = fma(eb[g], c, ar0);      ai0 = fma(ob[g], s, ai0);
            ar1 = fma(eb[g + 8], c, ar1);  ai1 = fma(ob[g + 8], s, ai1);
            ar2 = fma(eb[g + 16], c, ar2); ai2 = fma(ob[g + 16], s, ai2);
            ar3 = fma(eb[g + 24], c, ar3); ai3 = fma(ob[g + 24], s, ai3);
            double cn = c * w.x - s * w.y;
            double sn = s * w.x + c * w.y;
            c = cn; s = sn;
        }
        {
            double2 tm = TW8(tw_s, g * k1);
            R0 = make_double2(ar0 * tm.x - ai0 * tm.y, ar0 * tm.y + ai0 * tm.x);
        }
        {
            double2 tm = TW8(tw_s, (g + 8) * k1);
            R1 = make_double2(ar1 * tm.x - ai1 * tm.y, ar1 * tm.y + ai1 * tm.x);
        }
        {
            double2 tm = TW8(tw_s, (g + 16) * k1);
            R2 = make_double2(ar2 * tm.x - ai2 * tm.y, ar2 * tm.y + ai2 * tm.x);
        }
        {
            double2 tm = TW8(tw_s, (g + 24) * k1);
            R3 = make_double2(ar3 * tm.x - ai3 * tm.y, ar3 * tm.y + ai3 * tm.x);
        }
    }
    __syncthreads();   // xs reads done -> overwrite union with S

    uni[g * 32 + k1]        = R0;
    uni[(g + 8) * 32 + k1]  = R1;
    uni[(g + 16) * 32 + k1] = R2;
    uni[(g + 24) * 32 + k1] = R3;
    __syncthreads();

    // --- stage 2 (folded): X[k1+32k2] = sum_{t2<16} E[t2] W32^{t2 k2},
    //     E[t2] = S[t2] + (-1)^g S[t2+16]; bins k2 = g (A) and g+8 (B) via
    //     W32^{t2(g+8)} = W32^{t2 g} * (-i)^{t2}.
    {
        const double2 wa = TW8(tw_s, 32 * g);   // e^{-2 pi i g/32}
        const double sg = (g & 1) ? -1.0 : 1.0;
        double ca = 1.0, sa = 0.0;
        double Ar = 0, Ai = 0, Br = 0, Bi = 0;
#pragma unroll
        for (int u = 0; u < 4; ++u) {
            {
                const int t2 = 4 * u + 0;
                double2 S  = uni[t2 * 32 + k1];
                double2 S2 = uni[(t2 + 16) * 32 + k1];
                double Ex = fma(sg, S2.x, S.x);
                double Ey = fma(sg, S2.y, S.y);
                double P = fma(Ex, ca, -(Ey * sa));
                double Q = fma(Ex, sa,  (Ey * ca));
                Ar += P; Ai += Q; Br += P; Bi += Q;
                double cn = fma(ca, wa.x, -(sa * wa.y));
                double sn = fma(sa, wa.x,  (ca * wa.y));
                ca = cn; sa = sn;
            }
            {
                const int t2 = 4 * u + 1;
                double2 S  = uni[t2 * 32 + k1];
                double2 S2 = uni[(t2 + 16) * 32 + k1];
                double Ex = fma(sg, S2.x, S.x);
                double Ey = fma(sg, S2.y, S.y);
                double P = fma(Ex, ca, -(Ey * sa));
                double Q = fma(Ex, sa,  (Ey * ca));
                Ar += P; Ai += Q; Br += Q; Bi -= P;
                double cn = fma(ca, wa.x, -(sa * wa.y));
                double sn = fma(sa, wa.x,  (ca * wa.y));
                ca = cn; sa = sn;
            }
            {
                const int t2 = 4 * u + 2;
                double2 S  = uni[t2 * 32 + k1];
                double2 S2 = uni[(t2 + 16) * 32 + k1];
                double Ex = fma(sg, S2.x, S.x);
                double Ey = fma(sg, S2.y, S.y);
                double P = fma(Ex, ca, -(Ey * sa));
                double Q = fma(Ex, sa,  (Ey * ca));
                Ar += P; Ai += Q; Br -= P; Bi -= Q;
                double cn = fma(ca, wa.x, -(sa * wa.y));
                double sn = fma(sa, wa.x,  (ca * wa.y));
                ca = cn; sa = sn;
            }
            {
                const int t2 = 4 * u + 3;
                double2 S  = uni[t2 * 32 + k1];
                double2 S2 = uni[(t2 + 16) * 32 + k1];
                double Ex = fma(sg, S2.x, S.x);
                double Ey = fma(sg, S2.y, S.y);
                double P = fma(Ex, ca, -(Ey * sa));
                double Q = fma(Ex, sa,  (Ey * ca));
                Ar += P; Ai += Q; Br -= Q; Bi += P;
                double cn = fma(ca, wa.x, -(sa * wa.y));
                double sn = fma(sa, wa.x,  (ca * wa.y));
                ca = cn; sa = sn;
            }
        }
        const int ka = k1 + 32 * g;          // == tid
        const int kb = k1 + 32 * (g + 8);    // == tid + 256
        const size_t base = (size_t)pair * 512;

        // amp^2 keys (ordering identical to amp; sqrt deferred to winners)
        double a2a = Ar * Ar + Ai * Ai;
        double a2b = Br * Br + Bi * Bi;
        unsigned long long bba = __double_as_longlong(a2a);
        unsigned long long bbb = __double_as_longlong(a2b);
        double keya = __longlong_as_double((bba & ~1023ULL) |
                                           (unsigned long long)(1023 - ka));
        double keyb = __longlong_as_double((bbb & ~1023ULL) |
                                           (unsigned long long)(1023 - kb));
        if (ka == 0) keya = -1.0;   // DC excluded
        keys[base + ka] = keya;
        keys[base + kb] = keyb;
        phase[base + ka] = __float2half(atan2f((float)Ai, (float)Ar));
        phase[base + kb] = __float2half(atan2f((float)Bi, (float)Br));
    }
}

// ---------------------------------------------------------------------------
// K2b: top-32 per pair, one WAVE per pair.
// sel = (amp, phi, k, cos(2 pi k/1024))
// ---------------------------------------------------------------------------
__global__ __launch_bounds__(256) void topk_kernel(const double* __restrict__ keys,
                                                   const __half* __restrict__ phase,
                                                   float4* __restrict__ sel) {
    const int tid  = threadIdx.x;
    const int lane = tid & 63;
    const int pair = blockIdx.x * 4 + (tid >> 6);
    const size_t base = (size_t)pair * 512;

    double kreg[8];
#pragma unroll
    for (int j = 0; j < 8; ++j) kreg[j] = keys[base + j * 64 + lane];

    double win = -2.0;
    for (int r = 0; r < 32; ++r) {
        double m01 = fmax(kreg[0], kreg[1]);
        double m23 = fmax(kreg[2], kreg[3]);
        double m45 = fmax(kreg[4], kreg[5]);
        double m67 = fmax(kreg[6], kreg[7]);
        double m = fmax(fmax(m01, m23), fmax(m45, m67));
#pragma unroll
        for (int off = 1; off < 64; off <<= 1)
            m = fmax(m, __shfl_xor(m, off));
#pragma unroll
        for (int j = 0; j < 8; ++j)
            if (kreg[j] == m) kreg[j] = -2.0;   // exact bit match (keys unique)
        if (lane == r) win = m;
    }

    if (lane < 32) {
        unsigned long long b = __double_as_longlong(win);
        int k = 1023 - (int)(b & 1023ULL);
        float ph = __half2float(phase[base + k]);
        double amp = sqrt(win);   // win = amp^2 (packed bits, rel err 2^-43)
        float aout = (float)(2.0 * amp / (1024.0 + 1e-8));
        const float C = 6.28318530717958647692f / 1024.0f;
        float tkc = __cosf((float)k * C);
        sel[(size_t)pair * 32 + lane] = make_float4(aout, ph, (float)k, tkc);
    }
}

// ---------------------------------------------------------------------------
// K2-fallback (monolithic dft+topk), used if ws too small
// ---------------------------------------------------------------------------
__global__ __launch_bounds__(256) void dft_topk_kernel(const float* __restrict__ xt,
                                                       const double2* __restrict__ twg,
                                                       float2* __restrict__ stats,
                                                       float4* __restrict__ sel) {
    __shared__ double  xs_s[1024];
    __shared__ double2 tw_s[1024];
    __shared__ double2 S_s[32][32];
    __shared__ double2 spec_s[512];
    __shared__ double  amp_s[512];
    __shared__ double  red_s[16];
    __shared__ double  bc_s[2];

    const int tid  = threadIdx.x;
    const int pair = blockIdx.x;
    const float4 v = reinterpret_cast<const float4*>(xt + (size_t)pair * T_IN)[tid];
#pragma unroll
    for (int i = 0; i < 4; ++i) tw_s[tid + 256 * i] = twg[tid + 256 * i];

    double sum = (double)v.x + (double)v.y + (double)v.z + (double)v.w;
    double sq  = (double)v.x * v.x + (double)v.y * v.y +
                 (double)v.z * v.z + (double)v.w * v.w;
#pragma unroll
    for (int off = 32; off; off >>= 1) {
        sum += __shfl_down(sum, off);
        sq  += __shfl_down(sq, off);
    }
    const int wv = tid >> 6;
    if ((tid & 63) == 0) { red_s[wv] = sum; red_s[8 + wv] = sq; }
    __syncthreads();
    if (tid == 0) {
        double s = red_s[0] + red_s[1] + red_s[2] + red_s[3];
        double q = red_s[8] + red_s[9] + red_s[10] + red_s[11];
        double mean = s * (1.0 / 1024.0);
        double var  = (q - 1024.0 * mean * mean) * (1.0 / 1023.0);
        var = var > 0.0 ? var : 0.0;
        double stdp = sqrt(var) + 1e-8;
        bc_s[0] = mean; bc_s[1] = stdp;
        stats[pair] = make_float2((float)mean, (float)stdp);
    }
    __syncthreads();
    const double mean = bc_s[0];
    const double inv  = 1.0 / bc_s[1];
    {
        double z0 = ((double)v.x - mean) * inv;
        double z1 = ((double)v.y - mean) * inv;
        double z2 = ((double)v.z - mean) * inv;
        double z3 = ((double)v.w - mean) * inv;
        z0 = fmin(2.0, fmax(-2.0, z0)) + 1e-9;
        z1 = fmin(2.0, fmax(-2.0, z1)) + 1e-9;
        z2 = fmin(2.0, fmax(-2.0, z2)) + 1e-9;
        z3 = fmin(2.0, fmax(-2.0, z3)) + 1e-9;
        xs_s[tid * 4 + 0] = z0; xs_s[tid * 4 + 1] = z1;
        xs_s[tid * 4 + 2] = z2; xs_s[tid * 4 + 3] = z3;
    }
    __syncthreads();
    const int k1 = tid & 31;
    const int g  = tid >> 5;
    {
        const double2 w = tw_s[k1 * 32];
        double c = 1.0, s = 0.0;
        double ar0 = 0, ai0 = 0, ar1 = 0, ai1 = 0;
        double ar2 = 0, ai2 = 0, ar3 = 0, ai3 = 0;
#pragma unroll 4
        for (int t1 = 0; t1 < 32; ++t1) {
            const double* xb = &xs_s[t1 * 32];
            double x0 = xb[g], x1 = xb[g + 8], x2 = xb[g + 16], x3 = xb[g + 24];
            ar0 = fma(x0, c, ar0); ai0 = fma(x0, s, ai0);
            ar1 = fma(x1, c, ar1); ai1 = fma(x1, s, ai1);
            ar2 = fma(x2, c, ar2); ai2 = fma(x2, s, ai2);
            ar3 = fma(x3, c, ar3); ai3 = fma(x3, s, ai3);
            double cn = c * w.x - s * w.y;
            double sn = s * w.x + c * w.y;
            c = cn; s = sn;
        }
        { double2 tm = tw_s[g * k1];
          S_s[g][k1] = make_double2(ar0 * tm.x - ai0 * tm.y, ar0 * tm.y + ai0 * tm.x); }
        { double2 tm = tw_s[(g + 8) * k1];
          S_s[g + 8][k1] = make_double2(ar1 * tm.x - ai1 * tm.y, ar1 * tm.y + ai1 * tm.x); }
        { double2 tm = tw_s[(g + 16) * k1];
          S_s[g + 16][k1] = make_double2(ar2 * tm.x - ai2 * tm.y, ar2 * tm.y + ai2 * tm.x); }
        { double2 tm = tw_s[(g + 24) * k1];
          S_s[g + 24][k1] = make_double2(ar3 * tm.x - ai3 * tm.y, ar3 * tm.y + ai3 * tm.x); }
    }
    __syncthreads();
    {
        const double2 wa = tw_s[32 * g];
        const double2 wb = tw_s[32 * (g + 8)];
        double ca = 1.0, sa = 0.0, cb = 1.0, sb = 0.0;
        double Ar = 0, Ai = 0, Br = 0, Bi = 0;
#pragma unroll 4
        for (int t2 = 0; t2 < 32; ++t2) {
            double2 S = S_s[t2][k1];
            Ar += S.x * ca - S.y * sa; Ai += S.x * sa + S.y * ca;
            Br += S.x * cb - S.y * sb; Bi += S.x * sb + S.y * cb;
            double cn = ca * wa.x - sa * wa.y;
            double sn = sa * wa.x + ca * wa.y;
            ca = cn; sa = sn;
            cn = cb * wb.x - sb * wb.y;
            sn = sb * wb.x + cb * wb.y;
            cb = cn; sb = sn;
        }
        const int ka = k1 + 32 * g;
        const int kb = k1 + 32 * (g + 8);
        spec_s[ka] = make_double2(Ar, Ai);
        amp_s[ka]  = (ka == 0) ? -1.0 : sqrt(Ar * Ar + Ai * Ai);
        spec_s[kb] = make_double2(Br, Bi);
        amp_s[kb]  = sqrt(Br * Br + Bi * Bi);
    }
    __syncthreads();
    if (tid < 64) {
        const int lane = tid;
        double a0 = amp_s[lane * 8 + 0], a1 = amp_s[lane * 8 + 1];
        double a2 = amp_s[lane * 8 + 2], a3 = amp_s[lane * 8 + 3];
        double a4 = amp_s[lane * 8 + 4], a5 = amp_s[lane * 8 + 5];
        double a6 = amp_s[lane * 8 + 6], a7 = amp_s[lane * 8 + 7];
        int my_sel = 0;
        for (int r = 0; r < 32; ++r) {
            double vmax = a0; int li = 0;
            if (a1 > vmax) { vmax = a1; li = 1; }
            if (a2 > vmax) { vmax = a2; li = 2; }
            if (a3 > vmax) { vmax = a3; li = 3; }
            if (a4 > vmax) { vmax = a4; li = 4; }
            if (a5 > vmax) { vmax = a5; li = 5; }
            if (a6 > vmax) { vmax = a6; li = 6; }
            if (a7 > vmax) { vmax = a7; li = 7; }
            int gi = lane * 8 + li;
#pragma unroll
            for (int off = 1; off < 64; off <<= 1) {
                double ov = __shfl_xor(vmax, off);
                int    og = __shfl_xor(gi, off);
                if (ov > vmax || (ov == vmax && og < gi)) { vmax = ov; gi = og; }
            }
            if ((gi >> 3) == lane) {
                switch (gi & 7) {
                    case 0: a0 = -2.0; break; case 1: a1 = -2.0; break;
                    case 2: a2 = -2.0; break; case 3: a3 = -2.0; break;
                    case 4: a4 = -2.0; break; case 5: a5 = -2.0; break;
                    case 6: a6 = -2.0; break; case 7: a7 = -2.0; break;
                }
            }
            if (lane == r) my_sel = gi;
        }
        if (lane < 32) {
            const int k = my_sel;
            double2 sp  = spec_s[k];
            double aout = 2.0 * amp_s[k] / (1024.0 + 1e-8);
            double ph   = atan2(sp.y, sp.x);
            const float C = 6.28318530717958647692f / 1024.0f;
            float tkc = __cosf((float)k * C);
            sel[(size_t)pair * 32 + lane] =
                make_float4((float)aout, (float)ph, (float)k, tkc);
        }
    }
}

// ---------------------------------------------------------------------------
// K3 v6: Chebyshev reconstruction + t-periodicity.
// cos(ang0 + n*kC) via c_{n+1} = 2cos(kC)*c_n - c_{n-1}: 2 fma/term.
// out[t+1024] = out[t] for t<256 (angle periodic mod 2pi, exact).
// Block: 64 d-lanes x 4 waves x 16 t; 16 chunks of 64 t cover t<1024.
// ---------------------------------------------------------------------------
__global__ __launch_bounds__(256) void recon_kernel(const float4* __restrict__ sel,
                                                    const float2* __restrict__ stats,
                                                    float* __restrict__ out) {
    __shared__ float4 sel_s[32][65];
    __shared__ float2 st_s[64];
    const int bid   = blockIdx.x;
    const int chunk = bid & 15;        // 16 chunks x 64 t
    const int dt    = (bid >> 4) & 7;
    const int b     = bid >> 7;
    const int d0    = dt * 64;
    const int tid   = threadIdx.x;
#pragma unroll
    for (int it = 0; it < 8; ++it) {
        int i   = tid + it * 256;
        int j   = i & 31;
        int dls = i >> 5;
        sel_s[j][dls] = sel[((size_t)(b * D_DIM + d0 + dls)) * 32 + j];
    }
    if (tid < 64) st_s[tid] = stats[b * D_DIM + d0 + tid];
    __syncthreads();

    const int dl    = tid & 63;
    const int wvv   = tid >> 6;
    const int tbase = chunk * 64 + wvv * 16;   // < 1024

    float acc[16];
#pragma unroll
    for (int j = 0; j < 16; ++j) acc[j] = 0.0f;

    const float C = 6.28318530717958647692f / 1024.0f;
#pragma unroll 2
    for (int js = 0; js < 32; ++js) {
        float4 tr = sel_s[js][dl];       // (a, phi, k, cos(kC))
        const float a = tr.x;
        int k = (int)tr.z;
        float ck = tr.w;
        float sk = sqrtf(fmaxf(1.0f - ck * ck, 0.0f));   // k in [1,511] -> sin>0
        int mm0 = (k * tbase) & 1023;
        float ang0 = fmaf((float)mm0, C, tr.y);
        float s0, c0;
        __sincosf(ang0, &s0, &c0);
        float c1 = c0 * ck - s0 * sk;
        float K2 = ck + ck;
        acc[0] = fmaf(a, c0, acc[0]);
        acc[1] = fmaf(a, c1, acc[1]);
#pragma unroll
        for (int j = 2; j < 16; ++j) {
            float c2 = fmaf(K2, c1, -c0);
            acc[j] = fmaf(a, c2, acc[j]);
            c0 = c1; c1 = c2;
        }
    }
    const float2 st = st_s[dl];
#pragma unroll
    for (int j = 0; j < 16; ++j) {
        float o = fmaf(acc[j], st.y, st.x);
        int t = tbase + j;
        out[((size_t)b * T_OUT + t) * D_DIM + d0 + dl] = o;
        if (t < 256)
            out[((size_t)b * T_OUT + t + 1024) * D_DIM + d0 + dl] = o;
    }
}

// ---------------------------------------------------------------------------
extern "C" void kernel_launch(void* const* d_in, const int* in_sizes, int n_in,
                              void* d_out, int out_size, void* d_ws, size_t ws_size,
                              hipStream_t stream) {
    const float* x = (const float*)d_in[0];
    float* out = (float*)d_out;
    char* ws = (char*)d_ws;
    const size_t MB = 1024 * 1024;

    if (ws_size >= 39 * MB) {
        // split-path layout (total ~38.1 MB, no overlaps):
        float*   xt    = (float*)ws;                          // 16 MB  [0,16)
        double*  keys  = (double*)(ws + 16 * MB);             // 16 MB  [16,32)
        __half*  phase = (__half*)(ws + 32 * MB);             //  4 MB  [32,36)
        double2* tw    = (double2*)(ws + 36 * MB);            // 16 KB
        float2*  stats = (float2*)(ws + 36 * MB + 65536);     // 32 KB
        float4*  sel   = (float4*)(ws + 36 * MB + 131072);    //  2 MB

        transpose_kernel<<<dim3(8, 16, 8), 256, 0, stream>>>(x, xt, tw);
        dft_kernel<<<NPAIR, 256, 0, stream>>>(xt, tw, stats, keys, phase);
        topk_kernel<<<NPAIR / 4, 256, 0, stream>>>(keys, phase, sel);
        recon_kernel<<<1024, 256, 0, stream>>>(sel, stats, out);
    } else {
        // fallback
        float*   xt    = (float*)ws;                                    // 16 MB
        double2* tw    = (double2*)(ws + 16 * MB);                      // 16 KB
        float2*  stats = (float2*)(ws + 16 * MB + 16384);               // 32 KB
        float4*  sel   = (float4*)(ws + 16 * MB + 16384 + 32768);       //  2 MB

        transpose_kernel<<<dim3(8, 16, 8), 256, 0, stream>>>(x, xt, tw);
        dft_topk_kernel<<<NPAIR, 256, 0, stream>>>(xt, tw, stats, sel);
        recon_kernel<<<1024, 256, 0, stream>>>(sel, stats, out);
    }
}